// Round 13
// baseline (390.632 us; speedup 1.0000x reference)
//
#include <hip/hip_runtime.h>
#include <hip/hip_bf16.h>
#include <math.h>

#define DIMD   1024
#define NBATCH 4
#define NSEQ   8192
#define NTOK   (NBATCH * NSEQ)
#define NHEAVY 1024
#define NSEL   (NBATCH * NHEAVY)
#define DLIGHT 512
#define DHEAVY 4096
#define NITERS 50
#define BK     64

typedef __attribute__((ext_vector_type(8))) short short8;
typedef __attribute__((ext_vector_type(4))) float f32x4;
typedef __attribute__((ext_vector_type(4))) unsigned short u16x4;

__device__ __forceinline__ unsigned short f2bf(float f) {
    __hip_bfloat16 h = __float2bfloat16(f);
    union { __hip_bfloat16 h; unsigned short u; } cvt;
    cvt.h = h;
    return cvt.u;
}

__device__ __forceinline__ float bf2f(unsigned short u) {
    return __uint_as_float((unsigned)u << 16);
}

// Abramowitz-Stegun 7.1.26 erf, |eps|<=1.5e-7, single path (no branches).
__device__ __forceinline__ float gelu_fast(float x) {
    float ax = fabsf(x) * 0.7071067811865475f;
    float t = 1.0f / fmaf(0.3275911f, ax, 1.0f);
    float p = fmaf(t, 1.061405429f, -1.453152027f);
    p = fmaf(t, p, 1.421413741f);
    p = fmaf(t, p, -0.284496736f);
    p = fmaf(t, p, 0.254829592f);
    p = p * t;
    float e = __expf(-ax * ax);
    float erf_abs = fmaf(-p, e, 1.0f);
    float erf = copysignf(erf_abs, x);
    return 0.5f * x * (1.0f + erf);
}

__device__ __forceinline__ void gload_lds16(const void* g, void* l) {
    __builtin_amdgcn_global_load_lds(
        (const __attribute__((address_space(1))) void*)g,
        (__attribute__((address_space(3))) void*)l,
        16, 0, 0);
}

// ===== fused init: 4x cvt_transpose + xpass, 1-D block-range dispatch =====
// cvt: in[K][N] f32 -> out[N][K] bf16, optionally scaling row k by gamma[k].
// xpass: xb = bf16(x_row); sc = 32/max(||x||,1e-12); s = dot(x_row, rt) f64.
__global__ __launch_bounds__(256) void fused_init(
    const float* __restrict__ lw1, const float* __restrict__ lw2,
    const float* __restrict__ hw1, const float* __restrict__ hw2,
    const float* __restrict__ lgamma, const float* __restrict__ hgamma,
    short* __restrict__ wl1t, short* __restrict__ wl2t,
    short* __restrict__ wh1t, short* __restrict__ wh2t,
    const float* __restrict__ x, const float* __restrict__ rt,
    unsigned short* __restrict__ xb, float* __restrict__ sc,
    double* __restrict__ s_out) {
    __shared__ float tile[32][33];
    __shared__ float red[4];
    __shared__ double redd[4];
    int b = blockIdx.x;
    int tid = threadIdx.x;

    const float* cin = nullptr; short* cout = nullptr; const float* cg = nullptr;
    int cK = 0, cN = 0, cnx = 0, cb = 0;
    if (b < 512)        { cin = lw1; cout = wl1t; cg = lgamma; cK = DIMD;   cN = DLIGHT; cnx = 16;  cb = b; }
    else if (b < 1024)  { cin = lw2; cout = wl2t; cg = nullptr; cK = DLIGHT; cN = DIMD;  cnx = 32;  cb = b - 512; }
    else if (b < 5120)  { cin = hw1; cout = wh1t; cg = hgamma; cK = DIMD;   cN = DHEAVY; cnx = 128; cb = b - 1024; }
    else if (b < 9216)  { cin = hw2; cout = wh2t; cg = nullptr; cK = DHEAVY; cN = DIMD;  cnx = 32;  cb = b - 5120; }

    if (cin) {
        int n0 = (cb % cnx) * 32, k0 = (cb / cnx) * 32;
        int tx = tid & 31, ty = tid >> 5;  // (32, 8)
        #pragma unroll
        for (int j = 0; j < 4; j++) {
            int k = k0 + ty + 8 * j;
            float g = cg ? cg[k] : 1.0f;
            tile[ty + 8 * j][tx] = cin[(size_t)k * cN + (n0 + tx)] * g;
        }
        __syncthreads();
        #pragma unroll
        for (int j = 0; j < 4; j++)
            cout[(size_t)(n0 + ty + 8 * j) * cK + (k0 + tx)] =
                (short)f2bf(tile[tx][ty + 8 * j]);
        return;
    }

    int t = b - 9216;  // token id
    const float4* xr = (const float4*)(x + (size_t)t * DIMD);
    float4 v = xr[tid];
    ushort4 pk;
    pk.x = f2bf(v.x); pk.y = f2bf(v.y); pk.z = f2bf(v.z); pk.w = f2bf(v.w);
    ((ushort4*)(xb + (size_t)t * DIMD))[tid] = pk;

    float ss = v.x * v.x + v.y * v.y + v.z * v.z + v.w * v.w;
    float4 rv = ((const float4*)rt)[tid];
    double sd = (double)v.x * rv.x + (double)v.y * rv.y + (double)v.z * rv.z + (double)v.w * rv.w;
    #pragma unroll
    for (int off = 32; off > 0; off >>= 1) {
        ss += __shfl_down(ss, off);
        sd += __shfl_down(sd, off);
    }
    if ((tid & 63) == 0) { red[tid >> 6] = ss; redd[tid >> 6] = sd; }
    __syncthreads();
    if (tid == 0) {
        s_out[t] = redd[0] + redd[1] + redd[2] + redd[3];
        float tot = red[0] + red[1] + red[2] + red[3];
        sc[t] = 32.0f / fmaxf(sqrtf(tot), 1e-12f);
    }
}

// 50-step coordinate descent per batch row, f64, incremental piecewise-linear
// form: S(ea) = cnt + ea*T over the saturation partition (es_i*ea >= 1 -> 1).
// The partition changes only for elements crossing the threshold, so per
// iteration we reduce only flip DELTAS (usually zero -> shuffle chain skipped
// via wave-uniform ballot). Arithmetically equal to sum(min(es*ea,1)) mod
// associativity (~1e-11 drift vs the >=1e-4 tolerated boundary margin).
__global__ void descent_kern(const double* __restrict__ s, double* __restrict__ a_out) {
    int r = blockIdx.x, tid = threadIdx.x;  // 1024 threads, 16 waves
    int l = tid & 63, w = tid >> 6;
    const double* sr = s + (size_t)r * NSEQ;
    double es[8];
    #pragma unroll
    for (int i = 0; i < 8; i++) es[i] = exp(sr[tid + i * 1024]);

    __shared__ double2 red2[2][16];
    const double Kk = 1152.0;  // min(1024 * 9/8, 8192)
    double ea = exp(log(Kk) - log((double)NSEQ));  // e^{a_1}

    // initial partition + full (cnt, T) reduce
    unsigned satm = 0;
    double dT = 0.0; int dc = 0;
    #pragma unroll
    for (int i = 0; i < 8; i++) {
        if (es[i] * ea >= 1.0) { satm |= 1u << i; dc++; }
        else dT += es[i];
    }
    #pragma unroll
    for (int off = 32; off > 0; off >>= 1) {
        dT += __shfl_down(dT, off);
        dc += __shfl_down(dc, off);
    }
    if (l == 0) red2[0][w] = make_double2(dT, (double)dc);
    __syncthreads();
    double T = 0.0, cntd = 0.0;
    #pragma unroll
    for (int j = 0; j < 16; j++) { double2 q = red2[0][j]; T += q.x; cntd += q.y; }

    for (int it = 1; it < NITERS; it++) {
        double S = cntd + ea * T;
        ea = ea * (Kk / S);
        // flips vs new ea (rare)
        dT = 0.0; dc = 0;
        #pragma unroll
        for (int i = 0; i < 8; i++) {
            bool sat = (es[i] * ea >= 1.0);
            bool was = (satm >> i) & 1u;
            if (sat != was) {
                if (sat) { dT -= es[i]; dc++; satm |= 1u << i; }
                else     { dT += es[i]; dc--; satm &= ~(1u << i); }
            }
        }
        if (__ballot(dc != 0)) {  // wave-uniform: skip shuffle chain when no flips
            #pragma unroll
            for (int off = 32; off > 0; off >>= 1) {
                dT += __shfl_down(dT, off);
                dc += __shfl_down(dc, off);
            }
        }
        int pb = it & 1;
        if (l == 0) red2[pb][w] = make_double2(dT, (double)dc);
        __syncthreads();
        #pragma unroll
        for (int j = 0; j < 16; j++) { double2 q = red2[pb][j]; T += q.x; cntd += q.y; }
    }
    if (tid == 0) a_out[r] = log(ea);
}

// Selection per batch row (1 wave): tokens with s+a>=0 (plateau, lowest-index
// tie-break), fill by descending s. Also writes inv[token] = heavy slot.
__global__ void select_kern(const double* __restrict__ s, const double* __restrict__ a_arr,
                            int* __restrict__ sel, int* __restrict__ inv) {
    int r = blockIdx.x, l = threadIdx.x;  // 64 threads
    const double* sr = s + (size_t)r * NSEQ;
    double a = a_arr[r];
    __shared__ double sw[NSEQ];  // 64 KB
    int cnt = 0;
    for (int base = 0; base < NSEQ; base += 64) {
        int idx = base + l;
        double v = sr[idx];
        bool sat = (v + a) >= 0.0;
        sw[idx] = sat ? -1.0e300 : v;
        unsigned long long m = __ballot(sat);
        int pre = __popcll(m & ((1ull << l) - 1ull));
        if (sat) {
            int slot = cnt + pre;
            if (slot < NHEAVY) {
                sel[r * NHEAVY + slot] = r * NSEQ + idx;
                inv[r * NSEQ + idx] = r * NHEAVY + slot;
            }
        }
        cnt += (int)__popcll(m);
    }
    __syncthreads();
    for (int slot = cnt; slot < NHEAVY; slot++) {  // rarely taken fallback
        double best = -1.0e301; int bidx = NSEQ;
        for (int i = 0; i < NSEQ / 64; i++) {
            int idx = i * 64 + l;
            double v = sw[idx];
            if (v > best) { best = v; bidx = idx; }
        }
        #pragma unroll
        for (int off = 32; off > 0; off >>= 1) {
            double ov = __shfl_down(best, off);
            int oi = __shfl_down(bidx, off);
            if (ov > best || (ov == best && oi < bidx)) { best = ov; bidx = oi; }
        }
        bidx = __shfl(bidx, 0);
        if (l == 0) {
            sel[r * NHEAVY + slot] = r * NSEQ + bidx;
            inv[r * NSEQ + bidx] = r * NHEAVY + slot;
            sw[bidx] = -1.0e300;
        }
        __syncthreads();
    }
}

// hv[h][c] = hb2[c] + sum_j phb[j][h][c]   (dense heavy-output reduce, f32)
__global__ __launch_bounds__(256) void reduce_hv_kern(
    const unsigned short* __restrict__ phb, const float* __restrict__ hb2,
    float* __restrict__ hv, int nsk) {
    int h = blockIdx.x;          // 0..NSEL-1
    int c0 = threadIdx.x * 4;    // 256 threads x 4 cols
    f32x4 acc = *reinterpret_cast<const f32x4*>(hb2 + c0);
    for (int j = 0; j < nsk; j++) {
        u16x4 p = *reinterpret_cast<const u16x4*>(phb + ((size_t)j * NSEL + h) * DIMD + c0);
        #pragma unroll
        for (int rg = 0; rg < 4; rg++) acc[rg] += bf2f(p[rg]);
    }
    *reinterpret_cast<f32x4*>(hv + (size_t)h * DIMD + c0) = acc;
}

// ===== 256x256 8-phase GEMM (T2 swizzle + T3/T4 counted vmcnt + T5 setprio) =====
// C[M,N] = A[M,K]*Bt[N,K]^T, bf16 in / f32 acc. 8 waves (2M x 4N), per-wave 128x64.
// LDS: 2 dbuf x 2 halves x [128][64] bf16 for A and B = 128 KB.
// T2: st-swizzle byte^=((row&7)<<4) via pre-swizzled GLOBAL source (linear
// gload_lds dest) + swizzled ds_read addresses; kk*64 XORed INSIDE the column
// (bit 6 participates) — round-10 lesson.
// Schedule per K-tile t (4 quadrant phases): ds-read subtile; stage 1 half-tile
// (A(t+1) in phases 0-1 -> other buffer; B(t+2) in phases 2-3 -> same buffer,
// safe: B fully consumed in phase 0, two barriers earlier); phase 3: counted
// vmcnt(4) -> next tile landed; barrier; setprio(1) 16 MFMA setprio(0); barrier.
// MFMA operand-swapped: mfma(bf, af) -> lane owns row=(l&15), 4 consecutive cols.
// EPI 0: bf16 out = gelu(sc_row*acc + bias)      (GEMM1s; sc via sel if GATHER)
// EPI 2: bf16 partial[bz][m][n] = acc            (heavy GEMM2 split-K)
// EPI 3: f32 out = acc + bias [+ hv[inv[row]]]   (light GEMM2 fused, r11 form)
template <int EPI, bool GATHER>
__global__ __launch_bounds__(512, 2) void gemm256(
    const short* __restrict__ A, const short* __restrict__ Bt,
    const float* __restrict__ bias,
    const float* __restrict__ sc, const int* __restrict__ sel,
    const int* __restrict__ inv, const float* __restrict__ hv,
    float* __restrict__ outf, __hip_bfloat16* __restrict__ outb,
    int M, int N, int K) {
    __shared__ alignas(16) short As[2][2][128 * 64];  // [dbuf][half] 16 KB each
    __shared__ alignas(16) short Bs[2][2][128 * 64];

    // bijective XCD-aware swizzle on the flattened block id
    int nx = gridDim.x, ny = gridDim.y;
    int nwg = nx * ny * gridDim.z;
    int id = ((int)blockIdx.z * ny + blockIdx.y) * nx + blockIdx.x;
    if ((nwg & 7) == 0) id = (id & 7) * (nwg >> 3) + (id >> 3);
    int bxi = id % nx; int rem = id / nx;
    int byi = rem % ny; int bz = rem / ny;
    int klen = K / (int)gridDim.z, k0base = bz * klen;
    int bn0 = bxi * 256, bm0 = byi * 256;

    int tid = threadIdx.x;
    int l = tid & 63, w = tid >> 6;   // 8 waves
    int wr = w >> 2, wc = w & 3;      // 2 x 4

    f32x4 zero = {0.f, 0.f, 0.f, 0.f};
    f32x4 acc[8][4];
    #pragma unroll
    for (int i = 0; i < 8; i++)
        #pragma unroll
        for (int j = 0; j < 4; j++) acc[i][j] = zero;

    // staging source pointers: per (half h, issue j) thread covers LDS bytes
    // p = j*8192 + tid*16 of a [128][64]-bf16 half; fetch global at swizzled
    // offset o = p ^ ((p>>7 & 7) << 4)  (involution, 16B-chunk preserving).
    const short* aSrc[2][2];
    const short* bSrc[2][2];
    #pragma unroll
    for (int h = 0; h < 2; h++)
        #pragma unroll
        for (int j = 0; j < 2; j++) {
            int p = j * 8192 + tid * 16;
            int o = p ^ (((p >> 7) & 7) << 4);
            int lrow = o >> 7, colb = o & 127;
            int agrow = bm0 + h * 128 + lrow;
            int garow = GATHER ? sel[agrow] : agrow;
            aSrc[h][j] = A + (size_t)garow * K + (colb >> 1);
            bSrc[h][j] = Bt + (size_t)(bn0 + h * 128 + lrow) * K + (colb >> 1);
        }

    auto stageA = [&](int b, int h, int kof) {
        #pragma unroll
        for (int j = 0; j < 2; j++)
            gload_lds16(aSrc[h][j] + kof, &As[b][h][j * 4096 + w * 512]);
    };
    auto stageB = [&](int b, int h, int kof) {
        #pragma unroll
        for (int j = 0; j < 2; j++)
            gload_lds16(bSrc[h][j] + kof, &Bs[b][h][j * 4096 + w * 512]);
    };

    int nt = klen / BK;
    // prologue: A(0), B(0), B(1)
    stageA(0, 0, k0base); stageA(0, 1, k0base);
    stageB(0, 0, k0base); stageB(0, 1, k0base);
    if (nt > 1) {
        stageB(1, 0, k0base + BK); stageB(1, 1, k0base + BK);
        asm volatile("s_waitcnt vmcnt(4)" ::: "memory");
    } else {
        asm volatile("s_waitcnt vmcnt(0)" ::: "memory");
    }
    __builtin_amdgcn_s_barrier();
    asm volatile("" ::: "memory");

    // swizzled ds_read columns: row&7 == lr&7 for all fragment rows (subtile
    // strides are multiples of 8 rows): col_kk = ((l>>4)*16 + kk*64) ^ swz.
    const int lr = l & 15;
    const int swz = (lr & 7) << 4;
    const int rbase = lr * 128;
    const int colk[2] = { (((l >> 4) * 16)) ^ swz, (((l >> 4) * 16) + 64) ^ swz };

    short8 bfr[4][2];
    for (int t = 0; t < nt; ++t) {
        int d = t & 1;
        const char* aHalf = (const char*)(&As[d][wr][0]);
        const char* bHalf = (const char*)(&Bs[d][wc >> 1][0]) + (wc & 1) * 8192;
        #pragma unroll
        for (int q = 0; q < 4; q++) {
            if (q == 0) {
                #pragma unroll
                for (int ni = 0; ni < 4; ni++)
                    #pragma unroll
                    for (int kk = 0; kk < 2; kk++)
                        bfr[ni][kk] = *reinterpret_cast<const short8*>(bHalf + rbase + ni * 2048 + colk[kk]);
            }
            short8 afr[2][2];
            #pragma unroll
            for (int m2 = 0; m2 < 2; m2++)
                #pragma unroll
                for (int kk = 0; kk < 2; kk++)
                    afr[m2][kk] = *reinterpret_cast<const short8*>(aHalf + rbase + (q * 2 + m2) * 2048 + colk[kk]);
            if (q == 0 && t + 1 < nt) stageA(d ^ 1, 0, k0base + (t + 1) * BK);
            else if (q == 1 && t + 1 < nt) stageA(d ^ 1, 1, k0base + (t + 1) * BK);
            else if (q == 2 && t + 2 < nt) stageB(d, 0, k0base + (t + 2) * BK);
            else if (q == 3 && t + 2 < nt) stageB(d, 1, k0base + (t + 2) * BK);
            if (q == 3) {
                if (t + 2 < nt) asm volatile("s_waitcnt vmcnt(4)" ::: "memory");
                else            asm volatile("s_waitcnt vmcnt(0)" ::: "memory");
            }
            asm volatile("" ::: "memory");
            __builtin_amdgcn_s_barrier();
            asm volatile("" ::: "memory");
            __builtin_amdgcn_s_setprio(1);
            #pragma unroll
            for (int m2 = 0; m2 < 2; m2++)
                #pragma unroll
                for (int ni = 0; ni < 4; ni++)
                    #pragma unroll
                    for (int kk = 0; kk < 2; kk++)
                        acc[q * 2 + m2][ni] = __builtin_amdgcn_mfma_f32_16x16x32_bf16(
                            bfr[ni][kk], afr[m2][kk], acc[q * 2 + m2][ni], 0, 0, 0);
            __builtin_amdgcn_s_setprio(0);
            asm volatile("" ::: "memory");
            __builtin_amdgcn_s_barrier();
            asm volatile("" ::: "memory");
        }
    }

    // Swapped-D: row = bm0 + wr*128 + mi*16 + (l&15); cols = bn0 + wc*64 + ni*16 + (l>>4)*4 + reg
    int orow0 = bm0 + wr * 128, ocol0 = bn0 + wc * 64;
    const int lq = (l >> 4) * 4;
    #pragma unroll
    for (int mi = 0; mi < 8; mi++) {
        int row = orow0 + mi * 16 + lr;
        float scv = 0.0f;
        int iv = -1;
        if (EPI == 0) scv = sc[GATHER ? sel[row] : row];
        if (EPI == 3) iv = inv[row];
        #pragma unroll
        for (int ni = 0; ni < 4; ni++) {
            int c0 = ocol0 + ni * 16 + lq;
            if (EPI == 0) {
                f32x4 bv = *reinterpret_cast<const f32x4*>(bias + c0);
                u16x4 pk;
                #pragma unroll
                for (int rg = 0; rg < 4; rg++)
                    pk[rg] = f2bf(gelu_fast(fmaf(scv, acc[mi][ni][rg], bv[rg])));
                *reinterpret_cast<u16x4*>((unsigned short*)outb + (size_t)row * N + c0) = pk;
            } else if (EPI == 2) {
                u16x4 pk;
                #pragma unroll
                for (int rg = 0; rg < 4; rg++) pk[rg] = f2bf(acc[mi][ni][rg]);
                *reinterpret_cast<u16x4*>((unsigned short*)outb + ((size_t)bz * M + row) * (size_t)N + c0) = pk;
            } else {  // EPI == 3
                f32x4 bv = *reinterpret_cast<const f32x4*>(bias + c0);
                f32x4 v = acc[mi][ni] + bv;
                if (iv >= 0) {
                    f32x4 hvv = *reinterpret_cast<const f32x4*>(hv + (size_t)iv * DIMD + c0);
                    v = v + hvv;
                }
                *reinterpret_cast<f32x4*>(outf + (size_t)row * N + c0) = v;
            }
        }
    }
}

extern "C" void kernel_launch(void* const* d_in, const int* in_sizes, int n_in,
                              void* d_out, int out_size, void* d_ws, size_t ws_size,
                              hipStream_t stream) {
    (void)in_sizes; (void)n_in; (void)out_size;
    const float* x      = (const float*)d_in[0];
    const float* rt     = (const float*)d_in[1];
    const float* lgamma = (const float*)d_in[2];
    const float* lw1    = (const float*)d_in[3];
    const float* lb1    = (const float*)d_in[4];
    const float* lw2    = (const float*)d_in[5];
    const float* lb2    = (const float*)d_in[6];
    const float* hgamma = (const float*)d_in[7];
    const float* hw1    = (const float*)d_in[8];
    const float* hb1    = (const float*)d_in[9];
    const float* hw2    = (const float*)d_in[10];
    const float* hb2    = (const float*)d_in[11];
    float* out = (float*)d_out;

    auto rnd = [](size_t b) { return (b + 255) & ~(size_t)255; };
    size_t fixed = rnd(NTOK * sizeof(double))        // s
                 + rnd(256)                          // a
                 + rnd(NSEL * sizeof(int))           // sel
                 + rnd(NTOK * sizeof(int))           // inv
                 + rnd(NTOK * sizeof(float))         // sc
                 + rnd((size_t)DLIGHT * DIMD * 2)    // wl1t
                 + rnd((size_t)DIMD * DLIGHT * 2)    // wl2t
                 + rnd((size_t)DHEAVY * DIMD * 2)    // wh1t
                 + rnd((size_t)DIMD * DHEAVY * 2)    // wh2t
                 + rnd((size_t)NTOK * DIMD * 2)      // xb
                 + rnd((size_t)NSEL * DHEAVY * 2)    // hh (aliased by hl)
                 + rnd((size_t)NSEL * DIMD * 4);     // hv (f32)
    int nsk = 4;
    while (nsk > 1 && fixed + rnd((size_t)nsk * NSEL * DIMD * 2) > ws_size) nsk >>= 1;

    char* base = (char*)d_ws;
    size_t off = 0;
    auto alloc = [&](size_t bytes) -> void* {
        void* p = base + off;
        off += rnd(bytes);
        return p;
    };
    double* s     = (double*)alloc(NTOK * sizeof(double));
    double* a_arr = (double*)alloc(256);
    int*    sel   = (int*)alloc(NSEL * sizeof(int));
    int*    inv   = (int*)alloc(NTOK * sizeof(int));
    float*  sc    = (float*)alloc(NTOK * sizeof(float));
    short*  wl1t  = (short*)alloc((size_t)DLIGHT * DIMD * 2);
    short*  wl2t  = (short*)alloc((size_t)DIMD * DLIGHT * 2);
    short*  wh1t  = (short*)alloc((size_t)DHEAVY * DIMD * 2);
    short*  wh2t  = (short*)alloc((size_t)DIMD * DHEAVY * 2);
    short*  xb    = (short*)alloc((size_t)NTOK * DIMD * 2);
    short*  hh    = (short*)alloc((size_t)NSEL * DHEAVY * 2);
    float*  hv    = (float*)alloc((size_t)NSEL * DIMD * 4);
    short*  hl    = hh;  // light GEMM1 output aliases hh (dead after heavy GEMM2)
    short*  phb   = (short*)alloc((size_t)nsk * NSEL * DIMD * 2);

    hipMemsetAsync(inv, 0xFF, NTOK * sizeof(int), stream);  // inv = -1

    // fused init: 4x weight cvt_transpose (gamma folded into W1) + xpass
    fused_init<<<9216 + NTOK, 256, 0, stream>>>(
        lw1, lw2, hw1, hw2, lgamma, hgamma,
        wl1t, wl2t, wh1t, wh2t,
        x, rt, (unsigned short*)xb, sc, s);

    descent_kern<<<NBATCH, 1024, 0, stream>>>(s, a_arr);
    select_kern<<<NBATCH, 64, 0, stream>>>(s, a_arr, sel, inv);

    // heavy: GEMM1 (gather rows of xb, sc+gelu epi) -> hh; GEMM2 split-K -> phb; reduce -> hv
    gemm256<0, true><<<dim3(DHEAVY / 256, NSEL / 256), 512, 0, stream>>>(
        xb, wh1t, hb1, sc, sel, nullptr, nullptr,
        nullptr, (__hip_bfloat16*)hh, NSEL, DHEAVY, DIMD);
    gemm256<2, false><<<dim3(DIMD / 256, NSEL / 256, nsk), 512, 0, stream>>>(
        hh, wh2t, nullptr, nullptr, nullptr, nullptr, nullptr,
        nullptr, (__hip_bfloat16*)phb, NSEL, DIMD, DHEAVY);
    reduce_hv_kern<<<NSEL, 256, 0, stream>>>((const unsigned short*)phb, hb2, hv, nsk);

    // light: GEMM1 -> hl (aliases hh); GEMM2 fused (+hv via inv) -> out
    gemm256<0, false><<<dim3(DLIGHT / 256, NTOK / 256), 512, 0, stream>>>(
        xb, wl1t, lb1, sc, nullptr, nullptr, nullptr,
        nullptr, (__hip_bfloat16*)hl, NTOK, DLIGHT, DIMD);
    gemm256<3, false><<<dim3(DIMD / 256, NTOK / 256), 512, 0, stream>>>(
        hl, wl2t, lb2, nullptr, nullptr, inv, hv,
        out, nullptr, NTOK, DIMD, DLIGHT);
}

// Round 14
// 357.842 us; speedup vs baseline: 1.0916x; 1.0916x over previous
//
#include <hip/hip_runtime.h>
#include <hip/hip_bf16.h>
#include <math.h>

#define DIMD   1024
#define NBATCH 4
#define NSEQ   8192
#define NTOK   (NBATCH * NSEQ)
#define NHEAVY 1024
#define NSEL   (NBATCH * NHEAVY)
#define DLIGHT 512
#define DHEAVY 4096
#define NITERS 50
#define BK     64

typedef __attribute__((ext_vector_type(8))) short short8;
typedef __attribute__((ext_vector_type(4))) float f32x4;
typedef __attribute__((ext_vector_type(4))) unsigned short u16x4;

__device__ __forceinline__ unsigned short f2bf(float f) {
    __hip_bfloat16 h = __float2bfloat16(f);
    union { __hip_bfloat16 h; unsigned short u; } cvt;
    cvt.h = h;
    return cvt.u;
}

__device__ __forceinline__ float bf2f(unsigned short u) {
    return __uint_as_float((unsigned)u << 16);
}

// Abramowitz-Stegun 7.1.26 erf, |eps|<=1.5e-7, single path (no branches).
__device__ __forceinline__ float gelu_fast(float x) {
    float ax = fabsf(x) * 0.7071067811865475f;
    float t = 1.0f / fmaf(0.3275911f, ax, 1.0f);
    float p = fmaf(t, 1.061405429f, -1.453152027f);
    p = fmaf(t, p, 1.421413741f);
    p = fmaf(t, p, -0.284496736f);
    p = fmaf(t, p, 0.254829592f);
    p = p * t;
    float e = __expf(-ax * ax);
    float erf_abs = fmaf(-p, e, 1.0f);
    float erf = copysignf(erf_abs, x);
    return 0.5f * x * (1.0f + erf);
}

__device__ __forceinline__ void gload_lds16(const void* g, void* l) {
    __builtin_amdgcn_global_load_lds(
        (const __attribute__((address_space(1))) void*)g,
        (__attribute__((address_space(3))) void*)l,
        16, 0, 0);
}

// ===== fused init: 4x cvt_transpose + xpass, 1-D block-range dispatch =====
__global__ __launch_bounds__(256) void fused_init(
    const float* __restrict__ lw1, const float* __restrict__ lw2,
    const float* __restrict__ hw1, const float* __restrict__ hw2,
    const float* __restrict__ lgamma, const float* __restrict__ hgamma,
    short* __restrict__ wl1t, short* __restrict__ wl2t,
    short* __restrict__ wh1t, short* __restrict__ wh2t,
    const float* __restrict__ x, const float* __restrict__ rt,
    unsigned short* __restrict__ xb, float* __restrict__ sc,
    double* __restrict__ s_out) {
    __shared__ float tile[32][33];
    __shared__ float red[4];
    __shared__ double redd[4];
    int b = blockIdx.x;
    int tid = threadIdx.x;

    const float* cin = nullptr; short* cout = nullptr; const float* cg = nullptr;
    int cK = 0, cN = 0, cnx = 0, cb = 0;
    if (b < 512)        { cin = lw1; cout = wl1t; cg = lgamma; cK = DIMD;   cN = DLIGHT; cnx = 16;  cb = b; }
    else if (b < 1024)  { cin = lw2; cout = wl2t; cg = nullptr; cK = DLIGHT; cN = DIMD;  cnx = 32;  cb = b - 512; }
    else if (b < 5120)  { cin = hw1; cout = wh1t; cg = hgamma; cK = DIMD;   cN = DHEAVY; cnx = 128; cb = b - 1024; }
    else if (b < 9216)  { cin = hw2; cout = wh2t; cg = nullptr; cK = DHEAVY; cN = DIMD;  cnx = 32;  cb = b - 5120; }

    if (cin) {
        int n0 = (cb % cnx) * 32, k0 = (cb / cnx) * 32;
        int tx = tid & 31, ty = tid >> 5;  // (32, 8)
        #pragma unroll
        for (int j = 0; j < 4; j++) {
            int k = k0 + ty + 8 * j;
            float g = cg ? cg[k] : 1.0f;
            tile[ty + 8 * j][tx] = cin[(size_t)k * cN + (n0 + tx)] * g;
        }
        __syncthreads();
        #pragma unroll
        for (int j = 0; j < 4; j++)
            cout[(size_t)(n0 + ty + 8 * j) * cK + (k0 + tx)] =
                (short)f2bf(tile[tx][ty + 8 * j]);
        return;
    }

    int t = b - 9216;  // token id
    const float4* xr = (const float4*)(x + (size_t)t * DIMD);
    float4 v = xr[tid];
    ushort4 pk;
    pk.x = f2bf(v.x); pk.y = f2bf(v.y); pk.z = f2bf(v.z); pk.w = f2bf(v.w);
    ((ushort4*)(xb + (size_t)t * DIMD))[tid] = pk;

    float ss = v.x * v.x + v.y * v.y + v.z * v.z + v.w * v.w;
    float4 rv = ((const float4*)rt)[tid];
    double sd = (double)v.x * rv.x + (double)v.y * rv.y + (double)v.z * rv.z + (double)v.w * rv.w;
    #pragma unroll
    for (int off = 32; off > 0; off >>= 1) {
        ss += __shfl_down(ss, off);
        sd += __shfl_down(sd, off);
    }
    if ((tid & 63) == 0) { red[tid >> 6] = ss; redd[tid >> 6] = sd; }
    __syncthreads();
    if (tid == 0) {
        s_out[t] = redd[0] + redd[1] + redd[2] + redd[3];
        float tot = red[0] + red[1] + red[2] + red[3];
        sc[t] = 32.0f / fmaxf(sqrtf(tot), 1e-12f);
    }
}

// 50-step coordinate descent per batch row, f64, exp-domain (multiplicative,
// r12 form — measured 44 us; the r13 flip-delta variant regressed to 80).
// a <- logk + a - log(S)  ==  ea <- ea * (K/S), with S = sum_i min(es_i*ea, 1).
__global__ void descent_kern(const double* __restrict__ s, double* __restrict__ a_out) {
    int r = blockIdx.x, tid = threadIdx.x;  // 1024 threads
    const double* sr = s + (size_t)r * NSEQ;
    double es[8];
    #pragma unroll
    for (int i = 0; i < 8; i++) es[i] = exp(sr[tid + i * 1024]);
    __shared__ double red[2][16];
    const double Kk = 1152.0;  // min(1024 * 9/8, 8192)
    double ea = exp(log(Kk) - log((double)NSEQ));  // e^{a_1}
    for (int it = 1; it < NITERS; it++) {
        double loc = 0.0;
        #pragma unroll
        for (int i = 0; i < 8; i++) {
            double p = es[i] * ea;
            loc += (p < 1.0 ? p : 1.0);
        }
        #pragma unroll
        for (int off = 32; off > 0; off >>= 1) loc += __shfl_down(loc, off);
        int pb = it & 1;
        if ((tid & 63) == 0) red[pb][tid >> 6] = loc;
        __syncthreads();
        double S = 0.0;
        #pragma unroll
        for (int i = 0; i < 16; i++) S += red[pb][i];
        ea = ea * (Kk / S);  // redundant per-thread; deterministic, saves a 2nd barrier
    }
    if (tid == 0) a_out[r] = log(ea);
}

// Selection per batch row (1 wave): tokens with s+a>=0 (plateau, lowest-index
// tie-break), fill by descending s. Also writes inv[token] = heavy slot.
__global__ void select_kern(const double* __restrict__ s, const double* __restrict__ a_arr,
                            int* __restrict__ sel, int* __restrict__ inv) {
    int r = blockIdx.x, l = threadIdx.x;  // 64 threads
    const double* sr = s + (size_t)r * NSEQ;
    double a = a_arr[r];
    __shared__ double sw[NSEQ];  // 64 KB
    int cnt = 0;
    for (int base = 0; base < NSEQ; base += 64) {
        int idx = base + l;
        double v = sr[idx];
        bool sat = (v + a) >= 0.0;
        sw[idx] = sat ? -1.0e300 : v;
        unsigned long long m = __ballot(sat);
        int pre = __popcll(m & ((1ull << l) - 1ull));
        if (sat) {
            int slot = cnt + pre;
            if (slot < NHEAVY) {
                sel[r * NHEAVY + slot] = r * NSEQ + idx;
                inv[r * NSEQ + idx] = r * NHEAVY + slot;
            }
        }
        cnt += (int)__popcll(m);
    }
    __syncthreads();
    for (int slot = cnt; slot < NHEAVY; slot++) {  // rarely taken fallback
        double best = -1.0e301; int bidx = NSEQ;
        for (int i = 0; i < NSEQ / 64; i++) {
            int idx = i * 64 + l;
            double v = sw[idx];
            if (v > best) { best = v; bidx = idx; }
        }
        #pragma unroll
        for (int off = 32; off > 0; off >>= 1) {
            double ov = __shfl_down(best, off);
            int oi = __shfl_down(bidx, off);
            if (ov > best || (ov == best && oi < bidx)) { best = ov; bidx = oi; }
        }
        bidx = __shfl(bidx, 0);
        if (l == 0) {
            sel[r * NHEAVY + slot] = r * NSEQ + bidx;
            inv[r * NSEQ + bidx] = r * NHEAVY + slot;
            sw[bidx] = -1.0e300;
        }
        __syncthreads();
    }
}

// hv[h][c] = hb2[c] + sum_j phb[j][h][c]   (dense heavy-output reduce, f32)
__global__ __launch_bounds__(256) void reduce_hv_kern(
    const unsigned short* __restrict__ phb, const float* __restrict__ hb2,
    float* __restrict__ hv, int nsk) {
    int h = blockIdx.x;          // 0..NSEL-1
    int c0 = threadIdx.x * 4;    // 256 threads x 4 cols
    f32x4 acc = *reinterpret_cast<const f32x4*>(hb2 + c0);
    for (int j = 0; j < nsk; j++) {
        u16x4 p = *reinterpret_cast<const u16x4*>(phb + ((size_t)j * NSEL + h) * DIMD + c0);
        #pragma unroll
        for (int rg = 0; rg < 4; rg++) acc[rg] += bf2f(p[rg]);
    }
    *reinterpret_cast<f32x4*>(hv + (size_t)h * DIMD + c0) = acc;
}

// ===== 256x256 8-phase GEMM (T2 swizzle + T3/T4 counted vmcnt + T5 setprio) =====
// Sync discipline per m201 template: raw s_barrier pairs, per-phase
// s_waitcnt lgkmcnt(0) + sched_barrier(0) before the MFMA cluster, per-tile
// counted vmcnt asm (memory clobber = the tile-boundary compiler fence).
// NO blanket memory fences (r13 had 24/tile — they defeat compiler pipelining,
// cf. m141). Within-tile read reordering is safe: all ds_reads hit data staged
// >=1 tile ago; cross-wave WAR is protected by the barrier structure; cross-
// tile motion is blocked by the vmcnt memory clobber.
// T2 swizzle via pre-swizzled GLOBAL source + swizzled ds_read addresses;
// kk*64 XORed INSIDE the column (bit 6 participates) — round-10 lesson.
// Stage schedule per tile t: A(t+1) at q0/q1 (other buffer), B(t+2) at q2/q3
// (same buffer; B fully consumed at q0, two barriers earlier); q3: vmcnt(4).
// MFMA operand-swapped: mfma(bf, af) -> lane owns row=(l&15), 4 consecutive cols.
// EPI 0: bf16 out = gelu(sc_row*acc + bias)      (GEMM1s; sc via sel if GATHER)
// EPI 2: bf16 partial[bz][m][n] = acc            (heavy GEMM2 split-K)
// EPI 3: f32 out = acc + bias [+ hv[inv[row]]]   (light GEMM2 fused)
template <int EPI, bool GATHER>
__global__ __launch_bounds__(512) void gemm256(
    const short* __restrict__ A, const short* __restrict__ Bt,
    const float* __restrict__ bias,
    const float* __restrict__ sc, const int* __restrict__ sel,
    const int* __restrict__ inv, const float* __restrict__ hv,
    float* __restrict__ outf, __hip_bfloat16* __restrict__ outb,
    int M, int N, int K) {
    __shared__ alignas(16) short As[2][2][128 * 64];  // [dbuf][half] 16 KB each
    __shared__ alignas(16) short Bs[2][2][128 * 64];

    // bijective XCD-aware swizzle on the flattened block id
    int nx = gridDim.x, ny = gridDim.y;
    int nwg = nx * ny * gridDim.z;
    int id = ((int)blockIdx.z * ny + blockIdx.y) * nx + blockIdx.x;
    if ((nwg & 7) == 0) id = (id & 7) * (nwg >> 3) + (id >> 3);
    int bxi = id % nx; int rem = id / nx;
    int byi = rem % ny; int bz = rem / ny;
    int klen = K / (int)gridDim.z, k0base = bz * klen;
    int bn0 = bxi * 256, bm0 = byi * 256;

    int tid = threadIdx.x;
    int l = tid & 63, w = tid >> 6;   // 8 waves
    int wr = w >> 2, wc = w & 3;      // 2 x 4

    f32x4 zero = {0.f, 0.f, 0.f, 0.f};
    f32x4 acc[8][4];
    #pragma unroll
    for (int i = 0; i < 8; i++)
        #pragma unroll
        for (int j = 0; j < 4; j++) acc[i][j] = zero;

    // staging source pointers: per (half h, issue j) thread covers LDS bytes
    // p = j*8192 + tid*16 of a [128][64]-bf16 half; fetch global at swizzled
    // offset o = p ^ ((p>>7 & 7) << 4)  (involution, 16B-chunk preserving).
    const short* aSrc[2][2];
    const short* bSrc[2][2];
    #pragma unroll
    for (int h = 0; h < 2; h++)
        #pragma unroll
        for (int j = 0; j < 2; j++) {
            int p = j * 8192 + tid * 16;
            int o = p ^ (((p >> 7) & 7) << 4);
            int lrow = o >> 7, colb = o & 127;
            int agrow = bm0 + h * 128 + lrow;
            int garow = GATHER ? sel[agrow] : agrow;
            aSrc[h][j] = A + (size_t)garow * K + (colb >> 1);
            bSrc[h][j] = Bt + (size_t)(bn0 + h * 128 + lrow) * K + (colb >> 1);
        }

    auto stageA = [&](int b, int h, int kof) {
        #pragma unroll
        for (int j = 0; j < 2; j++)
            gload_lds16(aSrc[h][j] + kof, &As[b][h][j * 4096 + w * 512]);
    };
    auto stageB = [&](int b, int h, int kof) {
        #pragma unroll
        for (int j = 0; j < 2; j++)
            gload_lds16(bSrc[h][j] + kof, &Bs[b][h][j * 4096 + w * 512]);
    };

    int nt = klen / BK;
    // prologue: A(0), B(0), B(1)
    stageA(0, 0, k0base); stageA(0, 1, k0base);
    stageB(0, 0, k0base); stageB(0, 1, k0base);
    if (nt > 1) {
        stageB(1, 0, k0base + BK); stageB(1, 1, k0base + BK);
        asm volatile("s_waitcnt vmcnt(4)" ::: "memory");
    } else {
        asm volatile("s_waitcnt vmcnt(0)" ::: "memory");
    }
    __builtin_amdgcn_s_barrier();

    // swizzled ds_read columns: row&7 == lr&7 for all fragment rows (subtile
    // strides are multiples of 8 rows): col_kk = ((l>>4)*16 + kk*64) ^ swz.
    const int lr = l & 15;
    const int swz = (lr & 7) << 4;
    const int rbase = lr * 128;
    const int colk[2] = { (((l >> 4) * 16)) ^ swz, (((l >> 4) * 16) + 64) ^ swz };

    short8 bfr[4][2];
    for (int t = 0; t < nt; ++t) {
        int d = t & 1;
        const char* aHalf = (const char*)(&As[d][wr][0]);
        const char* bHalf = (const char*)(&Bs[d][wc >> 1][0]) + (wc & 1) * 8192;
        #pragma unroll
        for (int q = 0; q < 4; q++) {
            if (q == 0) {
                #pragma unroll
                for (int ni = 0; ni < 4; ni++)
                    #pragma unroll
                    for (int kk = 0; kk < 2; kk++)
                        bfr[ni][kk] = *reinterpret_cast<const short8*>(bHalf + rbase + ni * 2048 + colk[kk]);
            }
            short8 afr[2][2];
            #pragma unroll
            for (int m2 = 0; m2 < 2; m2++)
                #pragma unroll
                for (int kk = 0; kk < 2; kk++)
                    afr[m2][kk] = *reinterpret_cast<const short8*>(aHalf + rbase + (q * 2 + m2) * 2048 + colk[kk]);
            if (q == 0 && t + 1 < nt) stageA(d ^ 1, 0, k0base + (t + 1) * BK);
            else if (q == 1 && t + 1 < nt) stageA(d ^ 1, 1, k0base + (t + 1) * BK);
            else if (q == 2 && t + 2 < nt) stageB(d, 0, k0base + (t + 2) * BK);
            else if (q == 3 && t + 2 < nt) stageB(d, 1, k0base + (t + 2) * BK);
            if (q == 3) {
                if (t + 2 < nt) asm volatile("s_waitcnt vmcnt(4)" ::: "memory");
                else            asm volatile("s_waitcnt vmcnt(0)" ::: "memory");
            }
            __builtin_amdgcn_s_barrier();
            asm volatile("s_waitcnt lgkmcnt(0)" ::: "memory");
            __builtin_amdgcn_sched_barrier(0);  // rule #18: pin MFMAs below the wait
            __builtin_amdgcn_s_setprio(1);
            #pragma unroll
            for (int m2 = 0; m2 < 2; m2++)
                #pragma unroll
                for (int ni = 0; ni < 4; ni++)
                    #pragma unroll
                    for (int kk = 0; kk < 2; kk++)
                        acc[q * 2 + m2][ni] = __builtin_amdgcn_mfma_f32_16x16x32_bf16(
                            bfr[ni][kk], afr[m2][kk], acc[q * 2 + m2][ni], 0, 0, 0);
            __builtin_amdgcn_s_setprio(0);
            __builtin_amdgcn_s_barrier();
        }
    }

    // Swapped-D: row = bm0 + wr*128 + mi*16 + (l&15); cols = bn0 + wc*64 + ni*16 + (l>>4)*4 + reg
    int orow0 = bm0 + wr * 128, ocol0 = bn0 + wc * 64;
    const int lq = (l >> 4) * 4;
    #pragma unroll
    for (int mi = 0; mi < 8; mi++) {
        int row = orow0 + mi * 16 + lr;
        float scv = 0.0f;
        int iv = -1;
        if (EPI == 0) scv = sc[GATHER ? sel[row] : row];
        if (EPI == 3) iv = inv[row];
        #pragma unroll
        for (int ni = 0; ni < 4; ni++) {
            int c0 = ocol0 + ni * 16 + lq;
            if (EPI == 0) {
                f32x4 bv = *reinterpret_cast<const f32x4*>(bias + c0);
                u16x4 pk;
                #pragma unroll
                for (int rg = 0; rg < 4; rg++)
                    pk[rg] = f2bf(gelu_fast(fmaf(scv, acc[mi][ni][rg], bv[rg])));
                *reinterpret_cast<u16x4*>((unsigned short*)outb + (size_t)row * N + c0) = pk;
            } else if (EPI == 2) {
                u16x4 pk;
                #pragma unroll
                for (int rg = 0; rg < 4; rg++) pk[rg] = f2bf(acc[mi][ni][rg]);
                *reinterpret_cast<u16x4*>((unsigned short*)outb + ((size_t)bz * M + row) * (size_t)N + c0) = pk;
            } else {  // EPI == 3
                f32x4 bv = *reinterpret_cast<const f32x4*>(bias + c0);
                f32x4 v = acc[mi][ni] + bv;
                if (iv >= 0) {
                    f32x4 hvv = *reinterpret_cast<const f32x4*>(hv + (size_t)iv * DIMD + c0);
                    v = v + hvv;
                }
                *reinterpret_cast<f32x4*>(outf + (size_t)row * N + c0) = v;
            }
        }
    }
}

extern "C" void kernel_launch(void* const* d_in, const int* in_sizes, int n_in,
                              void* d_out, int out_size, void* d_ws, size_t ws_size,
                              hipStream_t stream) {
    (void)in_sizes; (void)n_in; (void)out_size;
    const float* x      = (const float*)d_in[0];
    const float* rt     = (const float*)d_in[1];
    const float* lgamma = (const float*)d_in[2];
    const float* lw1    = (const float*)d_in[3];
    const float* lb1    = (const float*)d_in[4];
    const float* lw2    = (const float*)d_in[5];
    const float* lb2    = (const float*)d_in[6];
    const float* hgamma = (const float*)d_in[7];
    const float* hw1    = (const float*)d_in[8];
    const float* hb1    = (const float*)d_in[9];
    const float* hw2    = (const float*)d_in[10];
    const float* hb2    = (const float*)d_in[11];
    float* out = (float*)d_out;

    auto rnd = [](size_t b) { return (b + 255) & ~(size_t)255; };
    size_t fixed = rnd(NTOK * sizeof(double))        // s
                 + rnd(256)                          // a
                 + rnd(NSEL * sizeof(int))           // sel
                 + rnd(NTOK * sizeof(int))           // inv
                 + rnd(NTOK * sizeof(float))         // sc
                 + rnd((size_t)DLIGHT * DIMD * 2)    // wl1t
                 + rnd((size_t)DIMD * DLIGHT * 2)    // wl2t
                 + rnd((size_t)DHEAVY * DIMD * 2)    // wh1t
                 + rnd((size_t)DIMD * DHEAVY * 2)    // wh2t
                 + rnd((size_t)NTOK * DIMD * 2)      // xb
                 + rnd((size_t)NSEL * DHEAVY * 2)    // hh (aliased by hl)
                 + rnd((size_t)NSEL * DIMD * 4);     // hv (f32)
    int nsk = 4;
    while (nsk > 1 && fixed + rnd((size_t)nsk * NSEL * DIMD * 2) > ws_size) nsk >>= 1;

    char* base = (char*)d_ws;
    size_t off = 0;
    auto alloc = [&](size_t bytes) -> void* {
        void* p = base + off;
        off += rnd(bytes);
        return p;
    };
    double* s     = (double*)alloc(NTOK * sizeof(double));
    double* a_arr = (double*)alloc(256);
    int*    sel   = (int*)alloc(NSEL * sizeof(int));
    int*    inv   = (int*)alloc(NTOK * sizeof(int));
    float*  sc    = (float*)alloc(NTOK * sizeof(float));
    short*  wl1t  = (short*)alloc((size_t)DLIGHT * DIMD * 2);
    short*  wl2t  = (short*)alloc((size_t)DIMD * DLIGHT * 2);
    short*  wh1t  = (short*)alloc((size_t)DHEAVY * DIMD * 2);
    short*  wh2t  = (short*)alloc((size_t)DIMD * DHEAVY * 2);
    short*  xb    = (short*)alloc((size_t)NTOK * DIMD * 2);
    short*  hh    = (short*)alloc((size_t)NSEL * DHEAVY * 2);
    float*  hv    = (float*)alloc((size_t)NSEL * DIMD * 4);
    short*  hl    = hh;  // light GEMM1 output aliases hh (dead after heavy GEMM2)
    short*  phb   = (short*)alloc((size_t)nsk * NSEL * DIMD * 2);

    hipMemsetAsync(inv, 0xFF, NTOK * sizeof(int), stream);  // inv = -1

    // fused init: 4x weight cvt_transpose (gamma folded into W1) + xpass
    fused_init<<<9216 + NTOK, 256, 0, stream>>>(
        lw1, lw2, hw1, hw2, lgamma, hgamma,
        wl1t, wl2t, wh1t, wh2t,
        x, rt, (unsigned short*)xb, sc, s);

    descent_kern<<<NBATCH, 1024, 0, stream>>>(s, a_arr);
    select_kern<<<NBATCH, 64, 0, stream>>>(s, a_arr, sel, inv);

    // heavy: GEMM1 (gather rows of xb, sc+gelu epi) -> hh; GEMM2 split-K -> phb; reduce -> hv
    gemm256<0, true><<<dim3(DHEAVY / 256, NSEL / 256), 512, 0, stream>>>(
        xb, wh1t, hb1, sc, sel, nullptr, nullptr,
        nullptr, (__hip_bfloat16*)hh, NSEL, DHEAVY, DIMD);
    gemm256<2, false><<<dim3(DIMD / 256, NSEL / 256, nsk), 512, 0, stream>>>(
        hh, wh2t, nullptr, nullptr, nullptr, nullptr, nullptr,
        nullptr, (__hip_bfloat16*)phb, NSEL, DIMD, DHEAVY);
    reduce_hv_kern<<<NSEL, 256, 0, stream>>>((const unsigned short*)phb, hb2, hv, nsk);

    // light: GEMM1 -> hl (aliases hh); GEMM2 fused (+hv via inv) -> out
    gemm256<0, false><<<dim3(DLIGHT / 256, NTOK / 256), 512, 0, stream>>>(
        xb, wl1t, lb1, sc, nullptr, nullptr, nullptr,
        nullptr, (__hip_bfloat16*)hl, NTOK, DLIGHT, DIMD);
    gemm256<3, false><<<dim3(DIMD / 256, NTOK / 256), 512, 0, stream>>>(
        hl, wl2t, lb2, nullptr, nullptr, inv, hv,
        out, nullptr, NTOK, DIMD, DLIGHT);
}

// Round 15
// 340.661 us; speedup vs baseline: 1.1467x; 1.0504x over previous
//
#include <hip/hip_runtime.h>
#include <hip/hip_bf16.h>
#include <math.h>

#define DIMD   1024
#define NBATCH 4
#define NSEQ   8192
#define NTOK   (NBATCH * NSEQ)
#define NHEAVY 1024
#define NSEL   (NBATCH * NHEAVY)
#define DLIGHT 512
#define DHEAVY 4096
#define NITERS 50
#define BK     64

typedef __attribute__((ext_vector_type(8))) short short8;
typedef __attribute__((ext_vector_type(4))) float f32x4;
typedef __attribute__((ext_vector_type(4))) unsigned short u16x4;

__device__ __forceinline__ unsigned short f2bf(float f) {
    __hip_bfloat16 h = __float2bfloat16(f);
    union { __hip_bfloat16 h; unsigned short u; } cvt;
    cvt.h = h;
    return cvt.u;
}

__device__ __forceinline__ float bf2f(unsigned short u) {
    return __uint_as_float((unsigned)u << 16);
}

// Abramowitz-Stegun 7.1.26 erf, |eps|<=1.5e-7, single path (no branches).
__device__ __forceinline__ float gelu_fast(float x) {
    float ax = fabsf(x) * 0.7071067811865475f;
    float t = 1.0f / fmaf(0.3275911f, ax, 1.0f);
    float p = fmaf(t, 1.061405429f, -1.453152027f);
    p = fmaf(t, p, 1.421413741f);
    p = fmaf(t, p, -0.284496736f);
    p = fmaf(t, p, 0.254829592f);
    p = p * t;
    float e = __expf(-ax * ax);
    float erf_abs = fmaf(-p, e, 1.0f);
    float erf = copysignf(erf_abs, x);
    return 0.5f * x * (1.0f + erf);
}

__device__ __forceinline__ void gload_lds16(const void* g, void* l) {
    __builtin_amdgcn_global_load_lds(
        (const __attribute__((address_space(1))) void*)g,
        (__attribute__((address_space(3))) void*)l,
        16, 0, 0);
}

// ===== fused init: 4x cvt_transpose + xpass, 1-D block-range dispatch =====
__global__ __launch_bounds__(256) void fused_init(
    const float* __restrict__ lw1, const float* __restrict__ lw2,
    const float* __restrict__ hw1, const float* __restrict__ hw2,
    const float* __restrict__ lgamma, const float* __restrict__ hgamma,
    short* __restrict__ wl1t, short* __restrict__ wl2t,
    short* __restrict__ wh1t, short* __restrict__ wh2t,
    const float* __restrict__ x, const float* __restrict__ rt,
    unsigned short* __restrict__ xb, float* __restrict__ sc,
    double* __restrict__ s_out) {
    __shared__ float tile[32][33];
    __shared__ float red[4];
    __shared__ double redd[4];
    int b = blockIdx.x;
    int tid = threadIdx.x;

    const float* cin = nullptr; short* cout = nullptr; const float* cg = nullptr;
    int cK = 0, cN = 0, cnx = 0, cb = 0;
    if (b < 512)        { cin = lw1; cout = wl1t; cg = lgamma; cK = DIMD;   cN = DLIGHT; cnx = 16;  cb = b; }
    else if (b < 1024)  { cin = lw2; cout = wl2t; cg = nullptr; cK = DLIGHT; cN = DIMD;  cnx = 32;  cb = b - 512; }
    else if (b < 5120)  { cin = hw1; cout = wh1t; cg = hgamma; cK = DIMD;   cN = DHEAVY; cnx = 128; cb = b - 1024; }
    else if (b < 9216)  { cin = hw2; cout = wh2t; cg = nullptr; cK = DHEAVY; cN = DIMD;  cnx = 32;  cb = b - 5120; }

    if (cin) {
        int n0 = (cb % cnx) * 32, k0 = (cb / cnx) * 32;
        int tx = tid & 31, ty = tid >> 5;  // (32, 8)
        #pragma unroll
        for (int j = 0; j < 4; j++) {
            int k = k0 + ty + 8 * j;
            float g = cg ? cg[k] : 1.0f;
            tile[ty + 8 * j][tx] = cin[(size_t)k * cN + (n0 + tx)] * g;
        }
        __syncthreads();
        #pragma unroll
        for (int j = 0; j < 4; j++)
            cout[(size_t)(n0 + ty + 8 * j) * cK + (k0 + tx)] =
                (short)f2bf(tile[tx][ty + 8 * j]);
        return;
    }

    int t = b - 9216;  // token id
    const float4* xr = (const float4*)(x + (size_t)t * DIMD);
    float4 v = xr[tid];
    ushort4 pk;
    pk.x = f2bf(v.x); pk.y = f2bf(v.y); pk.z = f2bf(v.z); pk.w = f2bf(v.w);
    ((ushort4*)(xb + (size_t)t * DIMD))[tid] = pk;

    float ss = v.x * v.x + v.y * v.y + v.z * v.z + v.w * v.w;
    float4 rv = ((const float4*)rt)[tid];
    double sd = (double)v.x * rv.x + (double)v.y * rv.y + (double)v.z * rv.z + (double)v.w * rv.w;
    #pragma unroll
    for (int off = 32; off > 0; off >>= 1) {
        ss += __shfl_down(ss, off);
        sd += __shfl_down(sd, off);
    }
    if ((tid & 63) == 0) { red[tid >> 6] = ss; redd[tid >> 6] = sd; }
    __syncthreads();
    if (tid == 0) {
        s_out[t] = redd[0] + redd[1] + redd[2] + redd[3];
        float tot = red[0] + red[1] + red[2] + red[3];
        sc[t] = 32.0f / fmaxf(sqrtf(tot), 1e-12f);
    }
}

// ===== megakernel: blocks 0-3 = 49-step descent (4 waves); blocks 4.. =
// light GEMM1 (r9-proven 128x128 2-phase, EPI0, no gather). 64 KB LDS ->
// 2 blocks/CU, so router blocks co-reside with GEMM blocks and the 44 us
// descent hides entirely under the ~55 us GEMM. Descent preserves the exact
// 49-application map ea <- ea*(K/S) (a_50 is path-dependent: contraction is
// only ~0.95/iter, so converging "smarter" would change the selection set —
// only the reduce tree order changes, ~1e-13 vs ~1e-2 boundary margin).
__global__ __launch_bounds__(256) void mega_kern(
    const double* __restrict__ s, double* __restrict__ a_out,
    const short* __restrict__ A, const short* __restrict__ Bt,
    const float* __restrict__ bias, const float* __restrict__ sc,
    __hip_bfloat16* __restrict__ outb) {
    __shared__ alignas(16) short As[2][128 * 64];  // 2 x 16 KB
    __shared__ alignas(16) short Bs[2][128 * 64];  // 2 x 16 KB
    __shared__ double redd[2][4];
    int tid = threadIdx.x;

    if (blockIdx.x < 4) {
        // ---- descent, 256 threads / 4 waves, es[32] per lane ----
        int r = blockIdx.x;
        int l = tid & 63, w = tid >> 6;
        const double* sr = s + (size_t)r * NSEQ;
        double es[32];
        #pragma unroll
        for (int i = 0; i < 32; i++) es[i] = exp(sr[tid + i * 256]);
        const double Kk = 1152.0;  // min(1024 * 9/8, 8192)
        double ea = exp(log(Kk) - log((double)NSEQ));  // e^{a_1}
        for (int it = 1; it < NITERS; it++) {
            double loc = 0.0;
            #pragma unroll
            for (int i = 0; i < 32; i++) {
                double p = es[i] * ea;
                loc += (p < 1.0 ? p : 1.0);
            }
            #pragma unroll
            for (int off = 32; off > 0; off >>= 1) loc += __shfl_down(loc, off);
            int pb = it & 1;
            if (l == 0) redd[pb][w] = loc;
            __syncthreads();
            double S = redd[pb][0] + redd[pb][1] + redd[pb][2] + redd[pb][3];
            ea = ea * (Kk / S);  // redundant per-thread; deterministic
        }
        if (tid == 0) a_out[r] = log(ea);
        return;
    }

    // ---- light GEMM1: C[M=NTOK, N=DLIGHT] = xb * wl1t^T, gelu(sc*acc+b) ----
    const int N = DLIGHT, K = DIMD;
    int gid = blockIdx.x - 4;          // 0..1023
    int id = (gid & 7) * (1024 >> 3) + (gid >> 3);  // bijective XCD swizzle
    int nx = N / 128;                  // 4
    int bxi = id % nx, byi = id / nx;
    int l = tid & 63, w = tid >> 6;
    int wr = w >> 1, wc = w & 1;
    int bn0 = bxi * 128, bm0 = byi * 128;

    f32x4 zero = {0.f, 0.f, 0.f, 0.f};
    f32x4 acc[4][4];
    #pragma unroll
    for (int i = 0; i < 4; i++)
        #pragma unroll
        for (int j = 0; j < 4; j++) acc[i][j] = zero;

    const int lrow = l & 15, lk = (l >> 4) * 8;
    int srow = tid >> 3, scol = (tid & 7) * 8;
    const short* AgC[4];
    const short* BgC[4];
    #pragma unroll
    for (int c = 0; c < 4; c++) {
        AgC[c] = A + (size_t)(bm0 + srow + c * 32) * K + scol;
        BgC[c] = Bt + (size_t)(bn0 + srow + c * 32) * K + scol;
    }
    const int sbase = (tid & ~63) * 8;

    auto stage = [&](int b, int k0) {
        #pragma unroll
        for (int c = 0; c < 4; c++) {
            gload_lds16(AgC[c] + k0, &As[b][sbase + c * 2048]);
            gload_lds16(BgC[c] + k0, &Bs[b][sbase + c * 2048]);
        }
    };

    int nt = K / 64;  // 16
    stage(0, 0);
    for (int t = 0; t < nt; ++t) {
        int cur = t & 1;
        if (t + 1 < nt) {
            stage(cur ^ 1, (t + 1) * 64);
            asm volatile("s_waitcnt vmcnt(8)" ::: "memory");
        } else {
            asm volatile("s_waitcnt vmcnt(0)" ::: "memory");
        }
        __builtin_amdgcn_s_barrier();
        asm volatile("" ::: "memory");
        #pragma unroll
        for (int kk = 0; kk < 2; kk++) {
            short8 af[4], bf[4];
            #pragma unroll
            for (int i = 0; i < 4; i++) {
                af[i] = *reinterpret_cast<const short8*>(&As[cur][(wr * 64 + i * 16 + lrow) * 64 + kk * 32 + lk]);
                bf[i] = *reinterpret_cast<const short8*>(&Bs[cur][(wc * 64 + i * 16 + lrow) * 64 + kk * 32 + lk]);
            }
            #pragma unroll
            for (int mi = 0; mi < 4; mi++)
                #pragma unroll
                for (int ni = 0; ni < 4; ni++)
                    acc[mi][ni] = __builtin_amdgcn_mfma_f32_16x16x32_bf16(bf[ni], af[mi], acc[mi][ni], 0, 0, 0);
        }
        if (t + 1 < nt) {
            asm volatile("" ::: "memory");
            __builtin_amdgcn_s_barrier();
            asm volatile("" ::: "memory");
        }
    }

    // Swapped-D epilogue: row = bm0+wr*64+mi*16+(l&15); cols = bn0+wc*64+ni*16+(l>>4)*4+reg
    int orow0 = bm0 + wr * 64, ocol0 = bn0 + wc * 64;
    const int lr = l & 15, lq = (l >> 4) * 4;
    #pragma unroll
    for (int mi = 0; mi < 4; mi++) {
        int row = orow0 + mi * 16 + lr;
        float scv = sc[row];
        #pragma unroll
        for (int ni = 0; ni < 4; ni++) {
            int c0 = ocol0 + ni * 16 + lq;
            f32x4 bv = *reinterpret_cast<const f32x4*>(bias + c0);
            u16x4 pk;
            #pragma unroll
            for (int rg = 0; rg < 4; rg++)
                pk[rg] = f2bf(gelu_fast(fmaf(scv, acc[mi][ni][rg], bv[rg])));
            *reinterpret_cast<u16x4*>((unsigned short*)outb + (size_t)row * N + c0) = pk;
        }
    }
}

// Selection per batch row (1 wave): tokens with s+a>=0 (plateau, lowest-index
// tie-break), fill by descending s. Also writes inv[token] = heavy slot.
__global__ void select_kern(const double* __restrict__ s, const double* __restrict__ a_arr,
                            int* __restrict__ sel, int* __restrict__ inv) {
    int r = blockIdx.x, l = threadIdx.x;  // 64 threads
    const double* sr = s + (size_t)r * NSEQ;
    double a = a_arr[r];
    __shared__ double sw[NSEQ];  // 64 KB
    int cnt = 0;
    for (int base = 0; base < NSEQ; base += 64) {
        int idx = base + l;
        double v = sr[idx];
        bool sat = (v + a) >= 0.0;
        sw[idx] = sat ? -1.0e300 : v;
        unsigned long long m = __ballot(sat);
        int pre = __popcll(m & ((1ull << l) - 1ull));
        if (sat) {
            int slot = cnt + pre;
            if (slot < NHEAVY) {
                sel[r * NHEAVY + slot] = r * NSEQ + idx;
                inv[r * NSEQ + idx] = r * NHEAVY + slot;
            }
        }
        cnt += (int)__popcll(m);
    }
    __syncthreads();
    for (int slot = cnt; slot < NHEAVY; slot++) {  // rarely taken fallback
        double best = -1.0e301; int bidx = NSEQ;
        for (int i = 0; i < NSEQ / 64; i++) {
            int idx = i * 64 + l;
            double v = sw[idx];
            if (v > best) { best = v; bidx = idx; }
        }
        #pragma unroll
        for (int off = 32; off > 0; off >>= 1) {
            double ov = __shfl_down(best, off);
            int oi = __shfl_down(bidx, off);
            if (ov > best || (ov == best && oi < bidx)) { best = ov; bidx = oi; }
        }
        bidx = __shfl(bidx, 0);
        if (l == 0) {
            sel[r * NHEAVY + slot] = r * NSEQ + bidx;
            inv[r * NSEQ + bidx] = r * NHEAVY + slot;
            sw[bidx] = -1.0e300;
        }
        __syncthreads();
    }
}

// hv[h][c] = hb2[c] + sum_j phb[j][h][c]   (dense heavy-output reduce, f32)
__global__ __launch_bounds__(256) void reduce_hv_kern(
    const unsigned short* __restrict__ phb, const float* __restrict__ hb2,
    float* __restrict__ hv, int nsk) {
    int h = blockIdx.x;          // 0..NSEL-1
    int c0 = threadIdx.x * 4;    // 256 threads x 4 cols
    f32x4 acc = *reinterpret_cast<const f32x4*>(hb2 + c0);
    for (int j = 0; j < nsk; j++) {
        u16x4 p = *reinterpret_cast<const u16x4*>(phb + ((size_t)j * NSEL + h) * DIMD + c0);
        #pragma unroll
        for (int rg = 0; rg < 4; rg++) acc[rg] += bf2f(p[rg]);
    }
    *reinterpret_cast<f32x4*>(hv + (size_t)h * DIMD + c0) = acc;
}

// ===== 256x256 8-phase GEMM (T2 swizzle + T3/T4 counted vmcnt + T5 setprio) =====
// (structure as r14; EPI3 out-stores are nontemporal to keep the 128 MB write
// stream from evicting A/B/hv in L2)
template <int EPI, bool GATHER>
__global__ __launch_bounds__(512) void gemm256(
    const short* __restrict__ A, const short* __restrict__ Bt,
    const float* __restrict__ bias,
    const float* __restrict__ sc, const int* __restrict__ sel,
    const int* __restrict__ inv, const float* __restrict__ hv,
    float* __restrict__ outf, __hip_bfloat16* __restrict__ outb,
    int M, int N, int K) {
    __shared__ alignas(16) short As[2][2][128 * 64];  // [dbuf][half] 16 KB each
    __shared__ alignas(16) short Bs[2][2][128 * 64];

    int nx = gridDim.x, ny = gridDim.y;
    int nwg = nx * ny * gridDim.z;
    int id = ((int)blockIdx.z * ny + blockIdx.y) * nx + blockIdx.x;
    if ((nwg & 7) == 0) id = (id & 7) * (nwg >> 3) + (id >> 3);
    int bxi = id % nx; int rem = id / nx;
    int byi = rem % ny; int bz = rem / ny;
    int klen = K / (int)gridDim.z, k0base = bz * klen;
    int bn0 = bxi * 256, bm0 = byi * 256;

    int tid = threadIdx.x;
    int l = tid & 63, w = tid >> 6;   // 8 waves
    int wr = w >> 2, wc = w & 3;      // 2 x 4

    f32x4 zero = {0.f, 0.f, 0.f, 0.f};
    f32x4 acc[8][4];
    #pragma unroll
    for (int i = 0; i < 8; i++)
        #pragma unroll
        for (int j = 0; j < 4; j++) acc[i][j] = zero;

    const short* aSrc[2][2];
    const short* bSrc[2][2];
    #pragma unroll
    for (int h = 0; h < 2; h++)
        #pragma unroll
        for (int j = 0; j < 2; j++) {
            int p = j * 8192 + tid * 16;
            int o = p ^ (((p >> 7) & 7) << 4);
            int lrow = o >> 7, colb = o & 127;
            int agrow = bm0 + h * 128 + lrow;
            int garow = GATHER ? sel[agrow] : agrow;
            aSrc[h][j] = A + (size_t)garow * K + (colb >> 1);
            bSrc[h][j] = Bt + (size_t)(bn0 + h * 128 + lrow) * K + (colb >> 1);
        }

    auto stageA = [&](int b, int h, int kof) {
        #pragma unroll
        for (int j = 0; j < 2; j++)
            gload_lds16(aSrc[h][j] + kof, &As[b][h][j * 4096 + w * 512]);
    };
    auto stageB = [&](int b, int h, int kof) {
        #pragma unroll
        for (int j = 0; j < 2; j++)
            gload_lds16(bSrc[h][j] + kof, &Bs[b][h][j * 4096 + w * 512]);
    };

    int nt = klen / BK;
    stageA(0, 0, k0base); stageA(0, 1, k0base);
    stageB(0, 0, k0base); stageB(0, 1, k0base);
    if (nt > 1) {
        stageB(1, 0, k0base + BK); stageB(1, 1, k0base + BK);
        asm volatile("s_waitcnt vmcnt(4)" ::: "memory");
    } else {
        asm volatile("s_waitcnt vmcnt(0)" ::: "memory");
    }
    __builtin_amdgcn_s_barrier();

    const int lr = l & 15;
    const int swz = (lr & 7) << 4;
    const int rbase = lr * 128;
    const int colk[2] = { (((l >> 4) * 16)) ^ swz, (((l >> 4) * 16) + 64) ^ swz };

    short8 bfr[4][2];
    for (int t = 0; t < nt; ++t) {
        int d = t & 1;
        const char* aHalf = (const char*)(&As[d][wr][0]);
        const char* bHalf = (const char*)(&Bs[d][wc >> 1][0]) + (wc & 1) * 8192;
        #pragma unroll
        for (int q = 0; q < 4; q++) {
            if (q == 0) {
                #pragma unroll
                for (int ni = 0; ni < 4; ni++)
                    #pragma unroll
                    for (int kk = 0; kk < 2; kk++)
                        bfr[ni][kk] = *reinterpret_cast<const short8*>(bHalf + rbase + ni * 2048 + colk[kk]);
            }
            short8 afr[2][2];
            #pragma unroll
            for (int m2 = 0; m2 < 2; m2++)
                #pragma unroll
                for (int kk = 0; kk < 2; kk++)
                    afr[m2][kk] = *reinterpret_cast<const short8*>(aHalf + rbase + (q * 2 + m2) * 2048 + colk[kk]);
            if (q == 0 && t + 1 < nt) stageA(d ^ 1, 0, k0base + (t + 1) * BK);
            else if (q == 1 && t + 1 < nt) stageA(d ^ 1, 1, k0base + (t + 1) * BK);
            else if (q == 2 && t + 2 < nt) stageB(d, 0, k0base + (t + 2) * BK);
            else if (q == 3 && t + 2 < nt) stageB(d, 1, k0base + (t + 2) * BK);
            if (q == 3) {
                if (t + 2 < nt) asm volatile("s_waitcnt vmcnt(4)" ::: "memory");
                else            asm volatile("s_waitcnt vmcnt(0)" ::: "memory");
            }
            __builtin_amdgcn_s_barrier();
            asm volatile("s_waitcnt lgkmcnt(0)" ::: "memory");
            __builtin_amdgcn_sched_barrier(0);  // rule #18
            __builtin_amdgcn_s_setprio(1);
            #pragma unroll
            for (int m2 = 0; m2 < 2; m2++)
                #pragma unroll
                for (int ni = 0; ni < 4; ni++)
                    #pragma unroll
                    for (int kk = 0; kk < 2; kk++)
                        acc[q * 2 + m2][ni] = __builtin_amdgcn_mfma_f32_16x16x32_bf16(
                            bfr[ni][kk], afr[m2][kk], acc[q * 2 + m2][ni], 0, 0, 0);
            __builtin_amdgcn_s_setprio(0);
            __builtin_amdgcn_s_barrier();
        }
    }

    int orow0 = bm0 + wr * 128, ocol0 = bn0 + wc * 64;
    const int lq = (l >> 4) * 4;
    #pragma unroll
    for (int mi = 0; mi < 8; mi++) {
        int row = orow0 + mi * 16 + lr;
        float scv = 0.0f;
        int iv = -1;
        if (EPI == 0) scv = sc[GATHER ? sel[row] : row];
        if (EPI == 3) iv = inv[row];
        #pragma unroll
        for (int ni = 0; ni < 4; ni++) {
            int c0 = ocol0 + ni * 16 + lq;
            if (EPI == 0) {
                f32x4 bv = *reinterpret_cast<const f32x4*>(bias + c0);
                u16x4 pk;
                #pragma unroll
                for (int rg = 0; rg < 4; rg++)
                    pk[rg] = f2bf(gelu_fast(fmaf(scv, acc[mi][ni][rg], bv[rg])));
                *reinterpret_cast<u16x4*>((unsigned short*)outb + (size_t)row * N + c0) = pk;
            } else if (EPI == 2) {
                u16x4 pk;
                #pragma unroll
                for (int rg = 0; rg < 4; rg++) pk[rg] = f2bf(acc[mi][ni][rg]);
                *reinterpret_cast<u16x4*>((unsigned short*)outb + ((size_t)bz * M + row) * (size_t)N + c0) = pk;
            } else {  // EPI == 3
                f32x4 bv = *reinterpret_cast<const f32x4*>(bias + c0);
                f32x4 v = acc[mi][ni] + bv;
                if (iv >= 0) {
                    f32x4 hvv = *reinterpret_cast<const f32x4*>(hv + (size_t)iv * DIMD + c0);
                    v = v + hvv;
                }
                __builtin_nontemporal_store(v, reinterpret_cast<f32x4*>(outf + (size_t)row * N + c0));
            }
        }
    }
}

extern "C" void kernel_launch(void* const* d_in, const int* in_sizes, int n_in,
                              void* d_out, int out_size, void* d_ws, size_t ws_size,
                              hipStream_t stream) {
    (void)in_sizes; (void)n_in; (void)out_size;
    const float* x      = (const float*)d_in[0];
    const float* rt     = (const float*)d_in[1];
    const float* lgamma = (const float*)d_in[2];
    const float* lw1    = (const float*)d_in[3];
    const float* lb1    = (const float*)d_in[4];
    const float* lw2    = (const float*)d_in[5];
    const float* lb2    = (const float*)d_in[6];
    const float* hgamma = (const float*)d_in[7];
    const float* hw1    = (const float*)d_in[8];
    const float* hb1    = (const float*)d_in[9];
    const float* hw2    = (const float*)d_in[10];
    const float* hb2    = (const float*)d_in[11];
    float* out = (float*)d_out;

    auto rnd = [](size_t b) { return (b + 255) & ~(size_t)255; };
    size_t fixed = rnd(NTOK * sizeof(double))        // s
                 + rnd(256)                          // a
                 + rnd(NSEL * sizeof(int))           // sel
                 + rnd(NTOK * sizeof(int))           // inv
                 + rnd(NTOK * sizeof(float))         // sc
                 + rnd((size_t)DLIGHT * DIMD * 2)    // wl1t
                 + rnd((size_t)DIMD * DLIGHT * 2)    // wl2t
                 + rnd((size_t)DHEAVY * DIMD * 2)    // wh1t
                 + rnd((size_t)DIMD * DHEAVY * 2)    // wh2t
                 + rnd((size_t)NTOK * DIMD * 2)      // xb
                 + rnd((size_t)NSEL * DHEAVY * 2)    // hh
                 + rnd((size_t)NTOK * DLIGHT * 2)    // hl (no longer aliases hh)
                 + rnd((size_t)NSEL * DIMD * 4);     // hv (f32)
    int nsk = 4;
    while (nsk > 1 && fixed + rnd((size_t)nsk * NSEL * DIMD * 2) > ws_size) nsk >>= 1;

    char* base = (char*)d_ws;
    size_t off = 0;
    auto alloc = [&](size_t bytes) -> void* {
        void* p = base + off;
        off += rnd(bytes);
        return p;
    };
    double* s     = (double*)alloc(NTOK * sizeof(double));
    double* a_arr = (double*)alloc(256);
    int*    sel   = (int*)alloc(NSEL * sizeof(int));
    int*    inv   = (int*)alloc(NTOK * sizeof(int));
    float*  sc    = (float*)alloc(NTOK * sizeof(float));
    short*  wl1t  = (short*)alloc((size_t)DLIGHT * DIMD * 2);
    short*  wl2t  = (short*)alloc((size_t)DIMD * DLIGHT * 2);
    short*  wh1t  = (short*)alloc((size_t)DHEAVY * DIMD * 2);
    short*  wh2t  = (short*)alloc((size_t)DIMD * DHEAVY * 2);
    short*  xb    = (short*)alloc((size_t)NTOK * DIMD * 2);
    short*  hh    = (short*)alloc((size_t)NSEL * DHEAVY * 2);
    short*  hl    = (short*)alloc((size_t)NTOK * DLIGHT * 2);  // own buffer now
    float*  hv    = (float*)alloc((size_t)NSEL * DIMD * 4);
    short*  phb   = (short*)alloc((size_t)nsk * NSEL * DIMD * 2);

    hipMemsetAsync(inv, 0xFF, NTOK * sizeof(int), stream);  // inv = -1

    // fused init: 4x weight cvt_transpose (gamma folded into W1) + xpass
    fused_init<<<9216 + NTOK, 256, 0, stream>>>(
        lw1, lw2, hw1, hw2, lgamma, hgamma,
        wl1t, wl2t, wh1t, wh2t,
        x, rt, (unsigned short*)xb, sc, s);

    // megakernel: descent (blocks 0-3) || light GEMM1 (blocks 4-1027)
    mega_kern<<<4 + 1024, 256, 0, stream>>>(
        s, a_arr, xb, wl1t, lb1, sc, (__hip_bfloat16*)hl);

    select_kern<<<NBATCH, 64, 0, stream>>>(s, a_arr, sel, inv);

    // heavy: GEMM1 (gather rows of xb, sc+gelu epi) -> hh; GEMM2 split-K -> phb; reduce -> hv
    gemm256<0, true><<<dim3(DHEAVY / 256, NSEL / 256), 512, 0, stream>>>(
        xb, wh1t, hb1, sc, sel, nullptr, nullptr,
        nullptr, (__hip_bfloat16*)hh, NSEL, DHEAVY, DIMD);
    gemm256<2, false><<<dim3(DIMD / 256, NSEL / 256, nsk), 512, 0, stream>>>(
        hh, wh2t, nullptr, nullptr, nullptr, nullptr, nullptr,
        nullptr, (__hip_bfloat16*)phb, NSEL, DIMD, DHEAVY);
    reduce_hv_kern<<<NSEL, 256, 0, stream>>>((const unsigned short*)phb, hb2, hv, nsk);

    // light GEMM2 fused (+hv via inv) -> out
    gemm256<3, false><<<dim3(DIMD / 256, NTOK / 256), 512, 0, stream>>>(
        hl, wl2t, lb2, nullptr, nullptr, inv, hv,
        out, nullptr, NTOK, DIMD, DLIGHT);
}

// Round 16
// 291.814 us; speedup vs baseline: 1.3386x; 1.1674x over previous
//
#include <hip/hip_runtime.h>
#include <hip/hip_bf16.h>
#include <math.h>

#define DIMD   1024
#define NBATCH 4
#define NSEQ   8192
#define NTOK   (NBATCH * NSEQ)
#define NHEAVY 1024
#define NSEL   (NBATCH * NHEAVY)
#define DLIGHT 512
#define DHEAVY 4096
#define NITERS 50
#define BK     64

typedef __attribute__((ext_vector_type(8))) short short8;
typedef __attribute__((ext_vector_type(4))) float f32x4;
typedef __attribute__((ext_vector_type(4))) unsigned short u16x4;

__device__ __forceinline__ unsigned short f2bf(float f) {
    __hip_bfloat16 h = __float2bfloat16(f);
    union { __hip_bfloat16 h; unsigned short u; } cvt;
    cvt.h = h;
    return cvt.u;
}

__device__ __forceinline__ float bf2f(unsigned short u) {
    return __uint_as_float((unsigned)u << 16);
}

// Abramowitz-Stegun 7.1.26 erf, |eps|<=1.5e-7, single path (no branches).
__device__ __forceinline__ float gelu_fast(float x) {
    float ax = fabsf(x) * 0.7071067811865475f;
    float t = 1.0f / fmaf(0.3275911f, ax, 1.0f);
    float p = fmaf(t, 1.061405429f, -1.453152027f);
    p = fmaf(t, p, 1.421413741f);
    p = fmaf(t, p, -0.284496736f);
    p = fmaf(t, p, 0.254829592f);
    p = p * t;
    float e = __expf(-ax * ax);
    float erf_abs = fmaf(-p, e, 1.0f);
    float erf = copysignf(erf_abs, x);
    return 0.5f * x * (1.0f + erf);
}

__device__ __forceinline__ void gload_lds16(const void* g, void* l) {
    __builtin_amdgcn_global_load_lds(
        (const __attribute__((address_space(1))) void*)g,
        (__attribute__((address_space(3))) void*)l,
        16, 0, 0);
}

// ===== fused init: 4x cvt_transpose + xpass (+inv=-1), 1-D block-range =====
__global__ __launch_bounds__(256) void fused_init(
    const float* __restrict__ lw1, const float* __restrict__ lw2,
    const float* __restrict__ hw1, const float* __restrict__ hw2,
    const float* __restrict__ lgamma, const float* __restrict__ hgamma,
    short* __restrict__ wl1t, short* __restrict__ wl2t,
    short* __restrict__ wh1t, short* __restrict__ wh2t,
    const float* __restrict__ x, const float* __restrict__ rt,
    unsigned short* __restrict__ xb, float* __restrict__ sc,
    double* __restrict__ s_out, int* __restrict__ inv) {
    __shared__ float tile[32][33];
    __shared__ float red[4];
    __shared__ double redd[4];
    int b = blockIdx.x;
    int tid = threadIdx.x;

    const float* cin = nullptr; short* cout = nullptr; const float* cg = nullptr;
    int cK = 0, cN = 0, cnx = 0, cb = 0;
    if (b < 512)        { cin = lw1; cout = wl1t; cg = lgamma; cK = DIMD;   cN = DLIGHT; cnx = 16;  cb = b; }
    else if (b < 1024)  { cin = lw2; cout = wl2t; cg = nullptr; cK = DLIGHT; cN = DIMD;  cnx = 32;  cb = b - 512; }
    else if (b < 5120)  { cin = hw1; cout = wh1t; cg = hgamma; cK = DIMD;   cN = DHEAVY; cnx = 128; cb = b - 1024; }
    else if (b < 9216)  { cin = hw2; cout = wh2t; cg = nullptr; cK = DHEAVY; cN = DIMD;  cnx = 32;  cb = b - 5120; }

    if (cin) {
        int n0 = (cb % cnx) * 32, k0 = (cb / cnx) * 32;
        int tx = tid & 31, ty = tid >> 5;  // (32, 8)
        #pragma unroll
        for (int j = 0; j < 4; j++) {
            int k = k0 + ty + 8 * j;
            float g = cg ? cg[k] : 1.0f;
            tile[ty + 8 * j][tx] = cin[(size_t)k * cN + (n0 + tx)] * g;
        }
        __syncthreads();
        #pragma unroll
        for (int j = 0; j < 4; j++)
            cout[(size_t)(n0 + ty + 8 * j) * cK + (k0 + tx)] =
                (short)f2bf(tile[tx][ty + 8 * j]);
        return;
    }

    int t = b - 9216;  // token id
    const float4* xr = (const float4*)(x + (size_t)t * DIMD);
    float4 v = xr[tid];
    ushort4 pk;
    pk.x = f2bf(v.x); pk.y = f2bf(v.y); pk.z = f2bf(v.z); pk.w = f2bf(v.w);
    ((ushort4*)(xb + (size_t)t * DIMD))[tid] = pk;

    float ss = v.x * v.x + v.y * v.y + v.z * v.z + v.w * v.w;
    float4 rv = ((const float4*)rt)[tid];
    double sd = (double)v.x * rv.x + (double)v.y * rv.y + (double)v.z * rv.z + (double)v.w * rv.w;
    #pragma unroll
    for (int off = 32; off > 0; off >>= 1) {
        ss += __shfl_down(ss, off);
        sd += __shfl_down(sd, off);
    }
    if ((tid & 63) == 0) { red[tid >> 6] = ss; redd[tid >> 6] = sd; }
    __syncthreads();
    if (tid == 0) {
        s_out[t] = redd[0] + redd[1] + redd[2] + redd[3];
        float tot = red[0] + red[1] + red[2] + red[3];
        sc[t] = 32.0f / fmaxf(sqrtf(tot), 1e-12f);
        inv[t] = -1;
    }
}

// ===== megakernel: blocks 0-3 = descent (exact 49-step map, r12 form) THEN
// single-wave select (reusing the 64 KB GEMM LDS as sw[]); blocks 4.. =
// light GEMM1 (128x128 2-phase, EPI0). Router fully hides under the GEMM.
__global__ __launch_bounds__(256) void mega_kern(
    const double* __restrict__ s, int* __restrict__ sel, int* __restrict__ inv,
    const short* __restrict__ A, const short* __restrict__ Bt,
    const float* __restrict__ bias, const float* __restrict__ sc,
    __hip_bfloat16* __restrict__ outb) {
    __shared__ alignas(16) char smem[65536 + 64];
    short (*As)[128 * 64] = reinterpret_cast<short (*)[128 * 64]>(smem);
    short (*Bs)[128 * 64] = reinterpret_cast<short (*)[128 * 64]>(smem + 32768);
    int tid = threadIdx.x;

    if (blockIdx.x < 4) {
        // ---- descent: 256 threads / 4 waves, es[32]/lane, exact r12 map ----
        int r = blockIdx.x;
        int lw = tid & 63, w = tid >> 6;
        double* redd = (double*)(smem + 65536);  // 8 doubles
        const double* sr = s + (size_t)r * NSEQ;
        double es[32];
        #pragma unroll
        for (int i = 0; i < 32; i++) es[i] = exp(sr[tid + i * 256]);
        const double Kk = 1152.0;  // min(1024 * 9/8, 8192)
        double ea = exp(log(Kk) - log((double)NSEQ));  // e^{a_1}
        for (int it = 1; it < NITERS; it++) {
            double loc = 0.0;
            #pragma unroll
            for (int i = 0; i < 32; i++) {
                double p = es[i] * ea;
                loc += (p < 1.0 ? p : 1.0);
            }
            #pragma unroll
            for (int off = 32; off > 0; off >>= 1) loc += __shfl_down(loc, off);
            int pb = (it & 1) * 4;
            if (lw == 0) redd[pb + w] = loc;
            __syncthreads();
            double S = redd[pb] + redd[pb + 1] + redd[pb + 2] + redd[pb + 3];
            ea = ea * (Kk / S);  // redundant per-thread; deterministic
        }
        double a = log(ea);
        __syncthreads();
        if (tid >= 64) return;

        // ---- select: single wave, sw[] reuses the GEMM LDS (64 KB) ----
        int l = tid;
        double* sw = (double*)smem;
        int cnt = 0;
        for (int base = 0; base < NSEQ; base += 64) {
            int idx = base + l;
            double v = sr[idx];
            bool sat = (v + a) >= 0.0;
            sw[idx] = sat ? -1.0e300 : v;
            unsigned long long m = __ballot(sat);
            int pre = __popcll(m & ((1ull << l) - 1ull));
            if (sat) {
                int slot = cnt + pre;
                if (slot < NHEAVY) {
                    sel[r * NHEAVY + slot] = r * NSEQ + idx;
                    inv[r * NSEQ + idx] = r * NHEAVY + slot;
                }
            }
            cnt += (int)__popcll(m);
        }
        for (int slot = cnt; slot < NHEAVY; slot++) {  // rarely taken fallback
            double best = -1.0e301; int bidx = NSEQ;
            for (int i = 0; i < NSEQ / 64; i++) {
                int idx = i * 64 + l;
                double v = sw[idx];
                if (v > best) { best = v; bidx = idx; }
            }
            #pragma unroll
            for (int off = 32; off > 0; off >>= 1) {
                double ov = __shfl_down(best, off);
                int oi = __shfl_down(bidx, off);
                if (ov > best || (ov == best && oi < bidx)) { best = ov; bidx = oi; }
            }
            bidx = __shfl(bidx, 0);
            if (l == 0) {
                sel[r * NHEAVY + slot] = r * NSEQ + bidx;
                inv[r * NSEQ + bidx] = r * NHEAVY + slot;
                sw[bidx] = -1.0e300;
            }
        }
        return;
    }

    // ---- light GEMM1: C[M=NTOK, N=DLIGHT] = xb * wl1t^T, gelu(sc*acc+b) ----
    const int N = DLIGHT, K = DIMD;
    int gid = blockIdx.x - 4;          // 0..1023
    int id = (gid & 7) * (1024 >> 3) + (gid >> 3);  // bijective XCD swizzle
    int nx = N / 128;                  // 4
    int bxi = id % nx, byi = id / nx;
    int l = tid & 63, w = tid >> 6;
    int wr = w >> 1, wc = w & 1;
    int bn0 = bxi * 128, bm0 = byi * 128;

    f32x4 zero = {0.f, 0.f, 0.f, 0.f};
    f32x4 acc[4][4];
    #pragma unroll
    for (int i = 0; i < 4; i++)
        #pragma unroll
        for (int j = 0; j < 4; j++) acc[i][j] = zero;

    const int lrow = l & 15, lk = (l >> 4) * 8;
    int srow = tid >> 3, scol = (tid & 7) * 8;
    const short* AgC[4];
    const short* BgC[4];
    #pragma unroll
    for (int c = 0; c < 4; c++) {
        AgC[c] = A + (size_t)(bm0 + srow + c * 32) * K + scol;
        BgC[c] = Bt + (size_t)(bn0 + srow + c * 32) * K + scol;
    }
    const int sbase = (tid & ~63) * 8;

    auto stage = [&](int b, int k0) {
        #pragma unroll
        for (int c = 0; c < 4; c++) {
            gload_lds16(AgC[c] + k0, &As[b][sbase + c * 2048]);
            gload_lds16(BgC[c] + k0, &Bs[b][sbase + c * 2048]);
        }
    };

    int nt = K / 64;  // 16
    stage(0, 0);
    for (int t = 0; t < nt; ++t) {
        int cur = t & 1;
        if (t + 1 < nt) {
            stage(cur ^ 1, (t + 1) * 64);
            asm volatile("s_waitcnt vmcnt(8)" ::: "memory");
        } else {
            asm volatile("s_waitcnt vmcnt(0)" ::: "memory");
        }
        __builtin_amdgcn_s_barrier();
        asm volatile("" ::: "memory");
        #pragma unroll
        for (int kk = 0; kk < 2; kk++) {
            short8 af[4], bf[4];
            #pragma unroll
            for (int i = 0; i < 4; i++) {
                af[i] = *reinterpret_cast<const short8*>(&As[cur][(wr * 64 + i * 16 + lrow) * 64 + kk * 32 + lk]);
                bf[i] = *reinterpret_cast<const short8*>(&Bs[cur][(wc * 64 + i * 16 + lrow) * 64 + kk * 32 + lk]);
            }
            #pragma unroll
            for (int mi = 0; mi < 4; mi++)
                #pragma unroll
                for (int ni = 0; ni < 4; ni++)
                    acc[mi][ni] = __builtin_amdgcn_mfma_f32_16x16x32_bf16(bf[ni], af[mi], acc[mi][ni], 0, 0, 0);
        }
        if (t + 1 < nt) {
            asm volatile("" ::: "memory");
            __builtin_amdgcn_s_barrier();
            asm volatile("" ::: "memory");
        }
    }

    int orow0 = bm0 + wr * 64, ocol0 = bn0 + wc * 64;
    const int lr = l & 15, lq = (l >> 4) * 4;
    #pragma unroll
    for (int mi = 0; mi < 4; mi++) {
        int row = orow0 + mi * 16 + lr;
        float scv = sc[row];
        #pragma unroll
        for (int ni = 0; ni < 4; ni++) {
            int c0 = ocol0 + ni * 16 + lq;
            f32x4 bv = *reinterpret_cast<const f32x4*>(bias + c0);
            u16x4 pk;
            #pragma unroll
            for (int rg = 0; rg < 4; rg++)
                pk[rg] = f2bf(gelu_fast(fmaf(scv, acc[mi][ni][rg], bv[rg])));
            *reinterpret_cast<u16x4*>((unsigned short*)outb + (size_t)row * N + c0) = pk;
        }
    }
}

// hv[h][c] = hb2[c] + sum_j phb[j][h][c]   (dense heavy-output reduce, f32)
__global__ __launch_bounds__(256) void reduce_hv_kern(
    const unsigned short* __restrict__ phb, const float* __restrict__ hb2,
    float* __restrict__ hv, int nsk) {
    int h = blockIdx.x;          // 0..NSEL-1
    int c0 = threadIdx.x * 4;    // 256 threads x 4 cols
    f32x4 acc = *reinterpret_cast<const f32x4*>(hb2 + c0);
    for (int j = 0; j < nsk; j++) {
        u16x4 p = *reinterpret_cast<const u16x4*>(phb + ((size_t)j * NSEL + h) * DIMD + c0);
        #pragma unroll
        for (int rg = 0; rg < 4; rg++) acc[rg] += bf2f(p[rg]);
    }
    *reinterpret_cast<f32x4*>(hv + (size_t)h * DIMD + c0) = acc;
}

// ===== 256x256 GEMM, TWO phases per K-tile (was 4) =====
// Theory (r15 accounting): per-phase fixed slop ~2.1kcy (8-wave barrier
// lockstep + drain + refill) dominated the 4-phase version (11.7kcy/tile vs
// m201's 3.3k). Halve phase count: 32 MFMA/phase, 4 barriers/tile, one
// lgkmcnt(0)+memory-clobber fence per phase (the m201-style compiler fence —
// also blocks gload hoisting above the barrier). Counted vmcnt(4) once/tile.
// Stage: A(t+1) both halves in phase 0 (other buffer); B(t+2) both halves in
// phase 1 (same buffer — safe: all B reads complete before phase-0-end
// barrier since lgkm drains precede MFMA which precedes the barrier).
// T2 swizzle via pre-swizzled GLOBAL source + swizzled ds_read addresses;
// kk*64 XORed INSIDE the column (bit 6 participates) — round-10 lesson.
// MFMA operand-swapped: mfma(bf, af) -> lane owns row=(l&15), 4 consecutive cols.
// EPI 0: bf16 out = gelu(sc_row*acc + bias)      (GEMM1s; sc via sel if GATHER)
// EPI 2: bf16 partial[bz][m][n] = acc            (heavy GEMM2 split-K)
// EPI 3: f32 out(NT) = acc + bias [+ hv[inv[row]]]  (light GEMM2 fused)
template <int EPI, bool GATHER>
__global__ __launch_bounds__(512) void gemm256(
    const short* __restrict__ A, const short* __restrict__ Bt,
    const float* __restrict__ bias,
    const float* __restrict__ sc, const int* __restrict__ sel,
    const int* __restrict__ inv, const float* __restrict__ hv,
    float* __restrict__ outf, __hip_bfloat16* __restrict__ outb,
    int M, int N, int K) {
    __shared__ alignas(16) short As[2][2][128 * 64];  // [dbuf][half] 16 KB each
    __shared__ alignas(16) short Bs[2][2][128 * 64];

    int nx = gridDim.x, ny = gridDim.y;
    int nwg = nx * ny * gridDim.z;
    int id = ((int)blockIdx.z * ny + blockIdx.y) * nx + blockIdx.x;
    if ((nwg & 7) == 0) id = (id & 7) * (nwg >> 3) + (id >> 3);
    int bxi = id % nx; int rem = id / nx;
    int byi = rem % ny; int bz = rem / ny;
    int klen = K / (int)gridDim.z, k0base = bz * klen;
    int bn0 = bxi * 256, bm0 = byi * 256;

    int tid = threadIdx.x;
    int l = tid & 63, w = tid >> 6;   // 8 waves
    int wr = w >> 2, wc = w & 3;      // 2 x 4

    f32x4 zero = {0.f, 0.f, 0.f, 0.f};
    f32x4 acc[8][4];
    #pragma unroll
    for (int i = 0; i < 8; i++)
        #pragma unroll
        for (int j = 0; j < 4; j++) acc[i][j] = zero;

    // pre-swizzled global staging sources (o = p ^ ((p>>7&7)<<4), involution)
    const short* aSrc[2][2];
    const short* bSrc[2][2];
    #pragma unroll
    for (int h = 0; h < 2; h++)
        #pragma unroll
        for (int j = 0; j < 2; j++) {
            int p = j * 8192 + tid * 16;
            int o = p ^ (((p >> 7) & 7) << 4);
            int lrow = o >> 7, colb = o & 127;
            int agrow = bm0 + h * 128 + lrow;
            int garow = GATHER ? sel[agrow] : agrow;
            aSrc[h][j] = A + (size_t)garow * K + (colb >> 1);
            bSrc[h][j] = Bt + (size_t)(bn0 + h * 128 + lrow) * K + (colb >> 1);
        }

    auto stageA = [&](int b, int h, int kof) {
        #pragma unroll
        for (int j = 0; j < 2; j++)
            gload_lds16(aSrc[h][j] + kof, &As[b][h][j * 4096 + w * 512]);
    };
    auto stageB = [&](int b, int h, int kof) {
        #pragma unroll
        for (int j = 0; j < 2; j++)
            gload_lds16(bSrc[h][j] + kof, &Bs[b][h][j * 4096 + w * 512]);
    };

    int nt = klen / BK;
    // prologue: A(0), B(0), B(1)
    stageA(0, 0, k0base); stageA(0, 1, k0base);
    stageB(0, 0, k0base); stageB(0, 1, k0base);
    if (nt > 1) {
        stageB(1, 0, k0base + BK); stageB(1, 1, k0base + BK);
        asm volatile("s_waitcnt vmcnt(4)" ::: "memory");
    } else {
        asm volatile("s_waitcnt vmcnt(0)" ::: "memory");
    }
    __builtin_amdgcn_s_barrier();

    // swizzled ds_read columns: col_kk = ((l>>4)*16 + kk*64) ^ ((lr&7)<<4)
    const int lr = l & 15;
    const int swz = (lr & 7) << 4;
    const int rbase = lr * 128;
    const int colk[2] = { (((l >> 4) * 16)) ^ swz, (((l >> 4) * 16) + 64) ^ swz };

    short8 bfr[4][2];
    for (int t = 0; t < nt; ++t) {
        int d = t & 1;
        const char* aHalf = (const char*)(&As[d][wr][0]);
        const char* bHalf = (const char*)(&Bs[d][wc >> 1][0]) + (wc & 1) * 8192;
        #pragma unroll
        for (int ph = 0; ph < 2; ph++) {
            if (ph == 0) {
                #pragma unroll
                for (int ni = 0; ni < 4; ni++)
                    #pragma unroll
                    for (int kk = 0; kk < 2; kk++)
                        bfr[ni][kk] = *reinterpret_cast<const short8*>(bHalf + rbase + ni * 2048 + colk[kk]);
            }
            short8 afr[4][2];
            #pragma unroll
            for (int m2 = 0; m2 < 4; m2++)
                #pragma unroll
                for (int kk = 0; kk < 2; kk++)
                    afr[m2][kk] = *reinterpret_cast<const short8*>(aHalf + rbase + (ph * 4 + m2) * 2048 + colk[kk]);
            if (ph == 0) {
                if (t + 1 < nt) {
                    stageA(d ^ 1, 0, k0base + (t + 1) * BK);
                    stageA(d ^ 1, 1, k0base + (t + 1) * BK);
                }
            } else {
                if (t + 2 < nt) {
                    stageB(d, 0, k0base + (t + 2) * BK);
                    stageB(d, 1, k0base + (t + 2) * BK);
                    asm volatile("s_waitcnt vmcnt(4)" ::: "memory");
                } else {
                    asm volatile("s_waitcnt vmcnt(0)" ::: "memory");
                }
            }
            __builtin_amdgcn_s_barrier();
            asm volatile("s_waitcnt lgkmcnt(0)" ::: "memory");  // fence + drain
            __builtin_amdgcn_s_setprio(1);
            #pragma unroll
            for (int m2 = 0; m2 < 4; m2++)
                #pragma unroll
                for (int ni = 0; ni < 4; ni++)
                    #pragma unroll
                    for (int kk = 0; kk < 2; kk++)
                        acc[ph * 4 + m2][ni] = __builtin_amdgcn_mfma_f32_16x16x32_bf16(
                            bfr[ni][kk], afr[m2][kk], acc[ph * 4 + m2][ni], 0, 0, 0);
            __builtin_amdgcn_s_setprio(0);
            __builtin_amdgcn_s_barrier();
        }
    }

    // Swapped-D: row = bm0 + wr*128 + mi*16 + (l&15); cols = bn0 + wc*64 + ni*16 + (l>>4)*4 + reg
    int orow0 = bm0 + wr * 128, ocol0 = bn0 + wc * 64;
    const int lq = (l >> 4) * 4;
    #pragma unroll
    for (int mi = 0; mi < 8; mi++) {
        int row = orow0 + mi * 16 + lr;
        float scv = 0.0f;
        int iv = -1;
        if (EPI == 0) scv = sc[GATHER ? sel[row] : row];
        if (EPI == 3) iv = inv[row];
        #pragma unroll
        for (int ni = 0; ni < 4; ni++) {
            int c0 = ocol0 + ni * 16 + lq;
            if (EPI == 0) {
                f32x4 bv = *reinterpret_cast<const f32x4*>(bias + c0);
                u16x4 pk;
                #pragma unroll
                for (int rg = 0; rg < 4; rg++)
                    pk[rg] = f2bf(gelu_fast(fmaf(scv, acc[mi][ni][rg], bv[rg])));
                *reinterpret_cast<u16x4*>((unsigned short*)outb + (size_t)row * N + c0) = pk;
            } else if (EPI == 2) {
                u16x4 pk;
                #pragma unroll
                for (int rg = 0; rg < 4; rg++) pk[rg] = f2bf(acc[mi][ni][rg]);
                *reinterpret_cast<u16x4*>((unsigned short*)outb + ((size_t)bz * M + row) * (size_t)N + c0) = pk;
            } else {  // EPI == 3
                f32x4 bv = *reinterpret_cast<const f32x4*>(bias + c0);
                f32x4 v = acc[mi][ni] + bv;
                if (iv >= 0) {
                    f32x4 hvv = *reinterpret_cast<const f32x4*>(hv + (size_t)iv * DIMD + c0);
                    v = v + hvv;
                }
                __builtin_nontemporal_store(v, reinterpret_cast<f32x4*>(outf + (size_t)row * N + c0));
            }
        }
    }
}

extern "C" void kernel_launch(void* const* d_in, const int* in_sizes, int n_in,
                              void* d_out, int out_size, void* d_ws, size_t ws_size,
                              hipStream_t stream) {
    (void)in_sizes; (void)n_in; (void)out_size;
    const float* x      = (const float*)d_in[0];
    const float* rt     = (const float*)d_in[1];
    const float* lgamma = (const float*)d_in[2];
    const float* lw1    = (const float*)d_in[3];
    const float* lb1    = (const float*)d_in[4];
    const float* lw2    = (const float*)d_in[5];
    const float* lb2    = (const float*)d_in[6];
    const float* hgamma = (const float*)d_in[7];
    const float* hw1    = (const float*)d_in[8];
    const float* hb1    = (const float*)d_in[9];
    const float* hw2    = (const float*)d_in[10];
    const float* hb2    = (const float*)d_in[11];
    float* out = (float*)d_out;

    auto rnd = [](size_t b) { return (b + 255) & ~(size_t)255; };
    size_t fixed = rnd(NTOK * sizeof(double))        // s
                 + rnd(NSEL * sizeof(int))           // sel
                 + rnd(NTOK * sizeof(int))           // inv
                 + rnd(NTOK * sizeof(float))         // sc
                 + rnd((size_t)DLIGHT * DIMD * 2)    // wl1t
                 + rnd((size_t)DIMD * DLIGHT * 2)    // wl2t
                 + rnd((size_t)DHEAVY * DIMD * 2)    // wh1t
                 + rnd((size_t)DIMD * DHEAVY * 2)    // wh2t
                 + rnd((size_t)NTOK * DIMD * 2)      // xb
                 + rnd((size_t)NSEL * DHEAVY * 2)    // hh
                 + rnd((size_t)NTOK * DLIGHT * 2)    // hl
                 + rnd((size_t)NSEL * DIMD * 4);     // hv (f32)
    int nsk = 4;
    while (nsk > 1 && fixed + rnd((size_t)nsk * NSEL * DIMD * 2) > ws_size) nsk >>= 1;

    char* base = (char*)d_ws;
    size_t off = 0;
    auto alloc = [&](size_t bytes) -> void* {
        void* p = base + off;
        off += rnd(bytes);
        return p;
    };
    double* s     = (double*)alloc(NTOK * sizeof(double));
    int*    sel   = (int*)alloc(NSEL * sizeof(int));
    int*    inv   = (int*)alloc(NTOK * sizeof(int));
    float*  sc    = (float*)alloc(NTOK * sizeof(float));
    short*  wl1t  = (short*)alloc((size_t)DLIGHT * DIMD * 2);
    short*  wl2t  = (short*)alloc((size_t)DIMD * DLIGHT * 2);
    short*  wh1t  = (short*)alloc((size_t)DHEAVY * DIMD * 2);
    short*  wh2t  = (short*)alloc((size_t)DIMD * DHEAVY * 2);
    short*  xb    = (short*)alloc((size_t)NTOK * DIMD * 2);
    short*  hh    = (short*)alloc((size_t)NSEL * DHEAVY * 2);
    short*  hl    = (short*)alloc((size_t)NTOK * DLIGHT * 2);
    float*  hv    = (float*)alloc((size_t)NSEL * DIMD * 4);
    short*  phb   = (short*)alloc((size_t)nsk * NSEL * DIMD * 2);

    // fused init: 4x weight cvt_transpose (gamma folded into W1) + xpass + inv=-1
    fused_init<<<9216 + NTOK, 256, 0, stream>>>(
        lw1, lw2, hw1, hw2, lgamma, hgamma,
        wl1t, wl2t, wh1t, wh2t,
        x, rt, (unsigned short*)xb, sc, s, inv);

    // megakernel: descent+select (blocks 0-3) || light GEMM1 (blocks 4-1027)
    mega_kern<<<4 + 1024, 256, 0, stream>>>(
        s, sel, inv, xb, wl1t, lb1, sc, (__hip_bfloat16*)hl);

    // heavy: GEMM1 (gather rows of xb, sc+gelu epi) -> hh; GEMM2 split-K -> phb; reduce -> hv
    gemm256<0, true><<<dim3(DHEAVY / 256, NSEL / 256), 512, 0, stream>>>(
        xb, wh1t, hb1, sc, sel, nullptr, nullptr,
        nullptr, (__hip_bfloat16*)hh, NSEL, DHEAVY, DIMD);
    gemm256<2, false><<<dim3(DIMD / 256, NSEL / 256, nsk), 512, 0, stream>>>(
        hh, wh2t, nullptr, nullptr, nullptr, nullptr, nullptr,
        nullptr, (__hip_bfloat16*)phb, NSEL, DIMD, DHEAVY);
    reduce_hv_kern<<<NSEL, 256, 0, stream>>>((const unsigned short*)phb, hb2, hv, nsk);

    // light GEMM2 fused (+hv via inv) -> out
    gemm256<3, false><<<dim3(DIMD / 256, NTOK / 256), 512, 0, stream>>>(
        hl, wl2t, lb2, nullptr, nullptr, inv, hv,
        out, nullptr, NTOK, DIMD, DLIGHT);
}

// Round 17
// 290.756 us; speedup vs baseline: 1.3435x; 1.0036x over previous
//
#include <hip/hip_runtime.h>
#include <hip/hip_bf16.h>
#include <math.h>

#define DIMD   1024
#define NBATCH 4
#define NSEQ   8192
#define NTOK   (NBATCH * NSEQ)
#define NHEAVY 1024
#define NSEL   (NBATCH * NHEAVY)
#define DLIGHT 512
#define DHEAVY 4096
#define NITERS 50
#define BK     64

typedef __attribute__((ext_vector_type(8))) short short8;
typedef __attribute__((ext_vector_type(4))) float f32x4;
typedef __attribute__((ext_vector_type(4))) unsigned short u16x4;

__device__ __forceinline__ unsigned short f2bf(float f) {
    __hip_bfloat16 h = __float2bfloat16(f);
    union { __hip_bfloat16 h; unsigned short u; } cvt;
    cvt.h = h;
    return cvt.u;
}

__device__ __forceinline__ float bf2f(unsigned short u) {
    return __uint_as_float((unsigned)u << 16);
}

// Abramowitz-Stegun 7.1.26 erf, |eps|<=1.5e-7, single path (no branches).
__device__ __forceinline__ float gelu_fast(float x) {
    float ax = fabsf(x) * 0.7071067811865475f;
    float t = 1.0f / fmaf(0.3275911f, ax, 1.0f);
    float p = fmaf(t, 1.061405429f, -1.453152027f);
    p = fmaf(t, p, 1.421413741f);
    p = fmaf(t, p, -0.284496736f);
    p = fmaf(t, p, 0.254829592f);
    p = p * t;
    float e = __expf(-ax * ax);
    float erf_abs = fmaf(-p, e, 1.0f);
    float erf = copysignf(erf_abs, x);
    return 0.5f * x * (1.0f + erf);
}

__device__ __forceinline__ void gload_lds16(const void* g, void* l) {
    __builtin_amdgcn_global_load_lds(
        (const __attribute__((address_space(1))) void*)g,
        (__attribute__((address_space(3))) void*)l,
        16, 0, 0);
}

// ===== fused init: 4x cvt_transpose + xpass (+inv=-1), 1-D block-range =====
__global__ __launch_bounds__(256) void fused_init(
    const float* __restrict__ lw1, const float* __restrict__ lw2,
    const float* __restrict__ hw1, const float* __restrict__ hw2,
    const float* __restrict__ lgamma, const float* __restrict__ hgamma,
    short* __restrict__ wl1t, short* __restrict__ wl2t,
    short* __restrict__ wh1t, short* __restrict__ wh2t,
    const float* __restrict__ x, const float* __restrict__ rt,
    unsigned short* __restrict__ xb, float* __restrict__ sc,
    double* __restrict__ s_out, int* __restrict__ inv) {
    __shared__ float tile[32][33];
    __shared__ float red[4];
    __shared__ double redd[4];
    int b = blockIdx.x;
    int tid = threadIdx.x;

    const float* cin = nullptr; short* cout = nullptr; const float* cg = nullptr;
    int cK = 0, cN = 0, cnx = 0, cb = 0;
    if (b < 512)        { cin = lw1; cout = wl1t; cg = lgamma; cK = DIMD;   cN = DLIGHT; cnx = 16;  cb = b; }
    else if (b < 1024)  { cin = lw2; cout = wl2t; cg = nullptr; cK = DLIGHT; cN = DIMD;  cnx = 32;  cb = b - 512; }
    else if (b < 5120)  { cin = hw1; cout = wh1t; cg = hgamma; cK = DIMD;   cN = DHEAVY; cnx = 128; cb = b - 1024; }
    else if (b < 9216)  { cin = hw2; cout = wh2t; cg = nullptr; cK = DHEAVY; cN = DIMD;  cnx = 32;  cb = b - 5120; }

    if (cin) {
        int n0 = (cb % cnx) * 32, k0 = (cb / cnx) * 32;
        int tx = tid & 31, ty = tid >> 5;  // (32, 8)
        #pragma unroll
        for (int j = 0; j < 4; j++) {
            int k = k0 + ty + 8 * j;
            float g = cg ? cg[k] : 1.0f;
            tile[ty + 8 * j][tx] = cin[(size_t)k * cN + (n0 + tx)] * g;
        }
        __syncthreads();
        #pragma unroll
        for (int j = 0; j < 4; j++)
            cout[(size_t)(n0 + ty + 8 * j) * cK + (k0 + tx)] =
                (short)f2bf(tile[tx][ty + 8 * j]);
        return;
    }

    int t = b - 9216;  // token id
    const float4* xr = (const float4*)(x + (size_t)t * DIMD);
    float4 v = xr[tid];
    ushort4 pk;
    pk.x = f2bf(v.x); pk.y = f2bf(v.y); pk.z = f2bf(v.z); pk.w = f2bf(v.w);
    ((ushort4*)(xb + (size_t)t * DIMD))[tid] = pk;

    float ss = v.x * v.x + v.y * v.y + v.z * v.z + v.w * v.w;
    float4 rv = ((const float4*)rt)[tid];
    double sd = (double)v.x * rv.x + (double)v.y * rv.y + (double)v.z * rv.z + (double)v.w * rv.w;
    #pragma unroll
    for (int off = 32; off > 0; off >>= 1) {
        ss += __shfl_down(ss, off);
        sd += __shfl_down(sd, off);
    }
    if ((tid & 63) == 0) { red[tid >> 6] = ss; redd[tid >> 6] = sd; }
    __syncthreads();
    if (tid == 0) {
        s_out[t] = redd[0] + redd[1] + redd[2] + redd[3];
        float tot = red[0] + red[1] + red[2] + red[3];
        sc[t] = 32.0f / fmaxf(sqrtf(tot), 1e-12f);
        inv[t] = -1;
    }
}

// ===== megakernel: blocks 0-3 = descent (exact 49-step map) THEN single-wave
// select (reusing the GEMM LDS as sw[]); blocks 4.. = light GEMM1 (128x128
// 2-phase, EPI0) — NOW with the T2 swizzle (r16 profile: 12.58M bank
// conflicts = saturated LDS pipe ~8.7kcy/iter/CU vs 1.2kcy MFMA wall).
// Swizzle: staging fetches global at o = p ^ ((p>>7&7)<<4) (LDS dest linear,
// rule #21); reads use col ^ ((row&7)<<4) with kk*64 INSIDE the XOR (r10).
__global__ __launch_bounds__(256) void mega_kern(
    const double* __restrict__ s, int* __restrict__ sel, int* __restrict__ inv,
    const short* __restrict__ A, const short* __restrict__ Bt,
    const float* __restrict__ bias, const float* __restrict__ sc,
    __hip_bfloat16* __restrict__ outb) {
    __shared__ alignas(16) char smem[65536 + 64];
    short (*As)[128 * 64] = reinterpret_cast<short (*)[128 * 64]>(smem);
    short (*Bs)[128 * 64] = reinterpret_cast<short (*)[128 * 64]>(smem + 32768);
    int tid = threadIdx.x;

    if (blockIdx.x < 4) {
        // ---- descent: 256 threads / 4 waves, es[32]/lane, exact r12 map ----
        int r = blockIdx.x;
        int lw = tid & 63, w = tid >> 6;
        double* redd = (double*)(smem + 65536);  // 8 doubles
        const double* sr = s + (size_t)r * NSEQ;
        double es[32];
        #pragma unroll
        for (int i = 0; i < 32; i++) es[i] = exp(sr[tid + i * 256]);
        const double Kk = 1152.0;  // min(1024 * 9/8, 8192)
        double ea = exp(log(Kk) - log((double)NSEQ));  // e^{a_1}
        for (int it = 1; it < NITERS; it++) {
            double loc = 0.0;
            #pragma unroll
            for (int i = 0; i < 32; i++) {
                double p = es[i] * ea;
                loc += (p < 1.0 ? p : 1.0);
            }
            #pragma unroll
            for (int off = 32; off > 0; off >>= 1) loc += __shfl_down(loc, off);
            int pb = (it & 1) * 4;
            if (lw == 0) redd[pb + w] = loc;
            __syncthreads();
            double S = redd[pb] + redd[pb + 1] + redd[pb + 2] + redd[pb + 3];
            ea = ea * (Kk / S);  // redundant per-thread; deterministic
        }
        double a = log(ea);
        __syncthreads();
        if (tid >= 64) return;

        // ---- select: single wave, sw[] reuses the GEMM LDS (64 KB) ----
        int l = tid;
        double* sw = (double*)smem;
        int cnt = 0;
        for (int base = 0; base < NSEQ; base += 64) {
            int idx = base + l;
            double v = sr[idx];
            bool sat = (v + a) >= 0.0;
            sw[idx] = sat ? -1.0e300 : v;
            unsigned long long m = __ballot(sat);
            int pre = __popcll(m & ((1ull << l) - 1ull));
            if (sat) {
                int slot = cnt + pre;
                if (slot < NHEAVY) {
                    sel[r * NHEAVY + slot] = r * NSEQ + idx;
                    inv[r * NSEQ + idx] = r * NHEAVY + slot;
                }
            }
            cnt += (int)__popcll(m);
        }
        for (int slot = cnt; slot < NHEAVY; slot++) {  // rarely taken fallback
            double best = -1.0e301; int bidx = NSEQ;
            for (int i = 0; i < NSEQ / 64; i++) {
                int idx = i * 64 + l;
                double v = sw[idx];
                if (v > best) { best = v; bidx = idx; }
            }
            #pragma unroll
            for (int off = 32; off > 0; off >>= 1) {
                double ov = __shfl_down(best, off);
                int oi = __shfl_down(bidx, off);
                if (ov > best || (ov == best && oi < bidx)) { best = ov; bidx = oi; }
            }
            bidx = __shfl(bidx, 0);
            if (l == 0) {
                sel[r * NHEAVY + slot] = r * NSEQ + bidx;
                inv[r * NSEQ + bidx] = r * NHEAVY + slot;
                sw[bidx] = -1.0e300;
            }
        }
        return;
    }

    // ---- light GEMM1: C[M=NTOK, N=DLIGHT] = xb * wl1t^T, gelu(sc*acc+b) ----
    const int N = DLIGHT, K = DIMD;
    int gid = blockIdx.x - 4;          // 0..1023
    int id = (gid & 7) * (1024 >> 3) + (gid >> 3);  // bijective XCD swizzle
    int nx = N / 128;                  // 4
    int bxi = id % nx, byi = id / nx;
    int l = tid & 63, w = tid >> 6;
    int wr = w >> 1, wc = w & 1;
    int bn0 = bxi * 128, bm0 = byi * 128;

    f32x4 zero = {0.f, 0.f, 0.f, 0.f};
    f32x4 acc[4][4];
    #pragma unroll
    for (int i = 0; i < 4; i++)
        #pragma unroll
        for (int j = 0; j < 4; j++) acc[i][j] = zero;

    // T2: pre-swizzled global staging sources. Per chunk c the thread covers
    // LDS byte p = c*4096 + tid*16 of the [128][128B] buffer; fetch global
    // at o = p ^ ((p>>7&7)<<4) (involution, 16B-chunk preserving).
    const short* AgC[4];
    const short* BgC[4];
    #pragma unroll
    for (int c = 0; c < 4; c++) {
        int p = c * 4096 + tid * 16;
        int o = p ^ (((p >> 7) & 7) << 4);
        int lrow = o >> 7, colb = o & 127;
        AgC[c] = A + (size_t)(bm0 + lrow) * K + (colb >> 1);
        BgC[c] = Bt + (size_t)(bn0 + lrow) * K + (colb >> 1);
    }
    const int sbase = (tid & ~63) * 8;  // wave-uniform LDS base (+lane*16B by HW)

    auto stage = [&](int b, int k0) {
        #pragma unroll
        for (int c = 0; c < 4; c++) {
            gload_lds16(AgC[c] + k0, &As[b][sbase + c * 2048]);
            gload_lds16(BgC[c] + k0, &Bs[b][sbase + c * 2048]);
        }
    };

    // swizzled ds_read columns: col_kk = ((l>>4)*16 + kk*64) ^ ((lr&7)<<4)
    const int lr16 = l & 15;
    const int swzm = (lr16 & 7) << 4;
    const int colkm[2] = { ((l >> 4) * 16) ^ swzm, (((l >> 4) * 16) + 64) ^ swzm };

    int nt = K / 64;  // 16
    stage(0, 0);
    for (int t = 0; t < nt; ++t) {
        int cur = t & 1;
        if (t + 1 < nt) {
            stage(cur ^ 1, (t + 1) * 64);
            asm volatile("s_waitcnt vmcnt(8)" ::: "memory");
        } else {
            asm volatile("s_waitcnt vmcnt(0)" ::: "memory");
        }
        __builtin_amdgcn_s_barrier();
        asm volatile("" ::: "memory");
        const char* aBuf = (const char*)&As[cur][0];
        const char* bBuf = (const char*)&Bs[cur][0];
        #pragma unroll
        for (int kk = 0; kk < 2; kk++) {
            short8 af[4], bf[4];
            #pragma unroll
            for (int i = 0; i < 4; i++) {
                af[i] = *reinterpret_cast<const short8*>(aBuf + (wr * 64 + i * 16 + lr16) * 128 + colkm[kk]);
                bf[i] = *reinterpret_cast<const short8*>(bBuf + (wc * 64 + i * 16 + lr16) * 128 + colkm[kk]);
            }
            #pragma unroll
            for (int mi = 0; mi < 4; mi++)
                #pragma unroll
                for (int ni = 0; ni < 4; ni++)
                    acc[mi][ni] = __builtin_amdgcn_mfma_f32_16x16x32_bf16(bf[ni], af[mi], acc[mi][ni], 0, 0, 0);
        }
        if (t + 1 < nt) {
            asm volatile("" ::: "memory");
            __builtin_amdgcn_s_barrier();
            asm volatile("" ::: "memory");
        }
    }

    int orow0 = bm0 + wr * 64, ocol0 = bn0 + wc * 64;
    const int lq = (l >> 4) * 4;
    #pragma unroll
    for (int mi = 0; mi < 4; mi++) {
        int row = orow0 + mi * 16 + lr16;
        float scv = sc[row];
        #pragma unroll
        for (int ni = 0; ni < 4; ni++) {
            int c0 = ocol0 + ni * 16 + lq;
            f32x4 bv = *reinterpret_cast<const f32x4*>(bias + c0);
            u16x4 pk;
            #pragma unroll
            for (int rg = 0; rg < 4; rg++)
                pk[rg] = f2bf(gelu_fast(fmaf(scv, acc[mi][ni][rg], bv[rg])));
            *reinterpret_cast<u16x4*>((unsigned short*)outb + (size_t)row * N + c0) = pk;
        }
    }
}

// hv[h][c] = hb2[c] + sum_j phb[j][h][c]   (dense heavy-output reduce, f32)
__global__ __launch_bounds__(256) void reduce_hv_kern(
    const unsigned short* __restrict__ phb, const float* __restrict__ hb2,
    float* __restrict__ hv, int nsk) {
    int h = blockIdx.x;          // 0..NSEL-1
    int c0 = threadIdx.x * 4;    // 256 threads x 4 cols
    f32x4 acc = *reinterpret_cast<const f32x4*>(hb2 + c0);
    for (int j = 0; j < nsk; j++) {
        u16x4 p = *reinterpret_cast<const u16x4*>(phb + ((size_t)j * NSEL + h) * DIMD + c0);
        #pragma unroll
        for (int rg = 0; rg < 4; rg++) acc[rg] += bf2f(p[rg]);
    }
    *reinterpret_cast<f32x4*>(hv + (size_t)h * DIMD + c0) = acc;
}

// ===== 256x256 GEMM, two phases per K-tile (r16 structure, unchanged) =====
// T2 swizzle (pre-swizzled global src + swizzled ds_read, kk*64 inside XOR),
// counted vmcnt(4) once/tile, setprio around MFMA, 4 barriers/tile.
// EPI 0: bf16 out = gelu(sc_row*acc + bias)      (GEMM1s; sc via sel if GATHER)
// EPI 2: bf16 partial[bz][m][n] = acc            (heavy GEMM2 split-K)
// EPI 3: f32 out(NT) = acc + bias [+ hv[inv[row]]]  (light GEMM2 fused)
template <int EPI, bool GATHER>
__global__ __launch_bounds__(512) void gemm256(
    const short* __restrict__ A, const short* __restrict__ Bt,
    const float* __restrict__ bias,
    const float* __restrict__ sc, const int* __restrict__ sel,
    const int* __restrict__ inv, const float* __restrict__ hv,
    float* __restrict__ outf, __hip_bfloat16* __restrict__ outb,
    int M, int N, int K) {
    __shared__ alignas(16) short As[2][2][128 * 64];  // [dbuf][half] 16 KB each
    __shared__ alignas(16) short Bs[2][2][128 * 64];

    int nx = gridDim.x, ny = gridDim.y;
    int nwg = nx * ny * gridDim.z;
    int id = ((int)blockIdx.z * ny + blockIdx.y) * nx + blockIdx.x;
    if ((nwg & 7) == 0) id = (id & 7) * (nwg >> 3) + (id >> 3);
    int bxi = id % nx; int rem = id / nx;
    int byi = rem % ny; int bz = rem / ny;
    int klen = K / (int)gridDim.z, k0base = bz * klen;
    int bn0 = bxi * 256, bm0 = byi * 256;

    int tid = threadIdx.x;
    int l = tid & 63, w = tid >> 6;   // 8 waves
    int wr = w >> 2, wc = w & 3;      // 2 x 4

    f32x4 zero = {0.f, 0.f, 0.f, 0.f};
    f32x4 acc[8][4];
    #pragma unroll
    for (int i = 0; i < 8; i++)
        #pragma unroll
        for (int j = 0; j < 4; j++) acc[i][j] = zero;

    // pre-swizzled global staging sources (o = p ^ ((p>>7&7)<<4), involution)
    const short* aSrc[2][2];
    const short* bSrc[2][2];
    #pragma unroll
    for (int h = 0; h < 2; h++)
        #pragma unroll
        for (int j = 0; j < 2; j++) {
            int p = j * 8192 + tid * 16;
            int o = p ^ (((p >> 7) & 7) << 4);
            int lrow = o >> 7, colb = o & 127;
            int agrow = bm0 + h * 128 + lrow;
            int garow = GATHER ? sel[agrow] : agrow;
            aSrc[h][j] = A + (size_t)garow * K + (colb >> 1);
            bSrc[h][j] = Bt + (size_t)(bn0 + h * 128 + lrow) * K + (colb >> 1);
        }

    auto stageA = [&](int b, int h, int kof) {
        #pragma unroll
        for (int j = 0; j < 2; j++)
            gload_lds16(aSrc[h][j] + kof, &As[b][h][j * 4096 + w * 512]);
    };
    auto stageB = [&](int b, int h, int kof) {
        #pragma unroll
        for (int j = 0; j < 2; j++)
            gload_lds16(bSrc[h][j] + kof, &Bs[b][h][j * 4096 + w * 512]);
    };

    int nt = klen / BK;
    // prologue: A(0), B(0), B(1)
    stageA(0, 0, k0base); stageA(0, 1, k0base);
    stageB(0, 0, k0base); stageB(0, 1, k0base);
    if (nt > 1) {
        stageB(1, 0, k0base + BK); stageB(1, 1, k0base + BK);
        asm volatile("s_waitcnt vmcnt(4)" ::: "memory");
    } else {
        asm volatile("s_waitcnt vmcnt(0)" ::: "memory");
    }
    __builtin_amdgcn_s_barrier();

    // swizzled ds_read columns: col_kk = ((l>>4)*16 + kk*64) ^ ((lr&7)<<4)
    const int lr = l & 15;
    const int swz = (lr & 7) << 4;
    const int rbase = lr * 128;
    const int colk[2] = { (((l >> 4) * 16)) ^ swz, (((l >> 4) * 16) + 64) ^ swz };

    short8 bfr[4][2];
    for (int t = 0; t < nt; ++t) {
        int d = t & 1;
        const char* aHalf = (const char*)(&As[d][wr][0]);
        const char* bHalf = (const char*)(&Bs[d][wc >> 1][0]) + (wc & 1) * 8192;
        #pragma unroll
        for (int ph = 0; ph < 2; ph++) {
            if (ph == 0) {
                #pragma unroll
                for (int ni = 0; ni < 4; ni++)
                    #pragma unroll
                    for (int kk = 0; kk < 2; kk++)
                        bfr[ni][kk] = *reinterpret_cast<const short8*>(bHalf + rbase + ni * 2048 + colk[kk]);
            }
            short8 afr[4][2];
            #pragma unroll
            for (int m2 = 0; m2 < 4; m2++)
                #pragma unroll
                for (int kk = 0; kk < 2; kk++)
                    afr[m2][kk] = *reinterpret_cast<const short8*>(aHalf + rbase + (ph * 4 + m2) * 2048 + colk[kk]);
            if (ph == 0) {
                if (t + 1 < nt) {
                    stageA(d ^ 1, 0, k0base + (t + 1) * BK);
                    stageA(d ^ 1, 1, k0base + (t + 1) * BK);
                }
            } else {
                if (t + 2 < nt) {
                    stageB(d, 0, k0base + (t + 2) * BK);
                    stageB(d, 1, k0base + (t + 2) * BK);
                    asm volatile("s_waitcnt vmcnt(4)" ::: "memory");
                } else {
                    asm volatile("s_waitcnt vmcnt(0)" ::: "memory");
                }
            }
            __builtin_amdgcn_s_barrier();
            asm volatile("s_waitcnt lgkmcnt(0)" ::: "memory");  // fence + drain
            __builtin_amdgcn_s_setprio(1);
            #pragma unroll
            for (int m2 = 0; m2 < 4; m2++)
                #pragma unroll
                for (int ni = 0; ni < 4; ni++)
                    #pragma unroll
                    for (int kk = 0; kk < 2; kk++)
                        acc[ph * 4 + m2][ni] = __builtin_amdgcn_mfma_f32_16x16x32_bf16(
                            bfr[ni][kk], afr[m2][kk], acc[ph * 4 + m2][ni], 0, 0, 0);
            __builtin_amdgcn_s_setprio(0);
            __builtin_amdgcn_s_barrier();
        }
    }

    // Swapped-D: row = bm0 + wr*128 + mi*16 + (l&15); cols = bn0 + wc*64 + ni*16 + (l>>4)*4 + reg
    int orow0 = bm0 + wr * 128, ocol0 = bn0 + wc * 64;
    const int lq = (l >> 4) * 4;
    #pragma unroll
    for (int mi = 0; mi < 8; mi++) {
        int row = orow0 + mi * 16 + lr;
        float scv = 0.0f;
        int iv = -1;
        if (EPI == 0) scv = sc[GATHER ? sel[row] : row];
        if (EPI == 3) iv = inv[row];
        #pragma unroll
        for (int ni = 0; ni < 4; ni++) {
            int c0 = ocol0 + ni * 16 + lq;
            if (EPI == 0) {
                f32x4 bv = *reinterpret_cast<const f32x4*>(bias + c0);
                u16x4 pk;
                #pragma unroll
                for (int rg = 0; rg < 4; rg++)
                    pk[rg] = f2bf(gelu_fast(fmaf(scv, acc[mi][ni][rg], bv[rg])));
                *reinterpret_cast<u16x4*>((unsigned short*)outb + (size_t)row * N + c0) = pk;
            } else if (EPI == 2) {
                u16x4 pk;
                #pragma unroll
                for (int rg = 0; rg < 4; rg++) pk[rg] = f2bf(acc[mi][ni][rg]);
                *reinterpret_cast<u16x4*>((unsigned short*)outb + ((size_t)bz * M + row) * (size_t)N + c0) = pk;
            } else {  // EPI == 3
                f32x4 bv = *reinterpret_cast<const f32x4*>(bias + c0);
                f32x4 v = acc[mi][ni] + bv;
                if (iv >= 0) {
                    f32x4 hvv = *reinterpret_cast<const f32x4*>(hv + (size_t)iv * DIMD + c0);
                    v = v + hvv;
                }
                __builtin_nontemporal_store(v, reinterpret_cast<f32x4*>(outf + (size_t)row * N + c0));
            }
        }
    }
}

extern "C" void kernel_launch(void* const* d_in, const int* in_sizes, int n_in,
                              void* d_out, int out_size, void* d_ws, size_t ws_size,
                              hipStream_t stream) {
    (void)in_sizes; (void)n_in; (void)out_size;
    const float* x      = (const float*)d_in[0];
    const float* rt     = (const float*)d_in[1];
    const float* lgamma = (const float*)d_in[2];
    const float* lw1    = (const float*)d_in[3];
    const float* lb1    = (const float*)d_in[4];
    const float* lw2    = (const float*)d_in[5];
    const float* lb2    = (const float*)d_in[6];
    const float* hgamma = (const float*)d_in[7];
    const float* hw1    = (const float*)d_in[8];
    const float* hb1    = (const float*)d_in[9];
    const float* hw2    = (const float*)d_in[10];
    const float* hb2    = (const float*)d_in[11];
    float* out = (float*)d_out;

    auto rnd = [](size_t b) { return (b + 255) & ~(size_t)255; };
    size_t fixed = rnd(NTOK * sizeof(double))        // s
                 + rnd(NSEL * sizeof(int))           // sel
                 + rnd(NTOK * sizeof(int))           // inv
                 + rnd(NTOK * sizeof(float))         // sc
                 + rnd((size_t)DLIGHT * DIMD * 2)    // wl1t
                 + rnd((size_t)DIMD * DLIGHT * 2)    // wl2t
                 + rnd((size_t)DHEAVY * DIMD * 2)    // wh1t
                 + rnd((size_t)DIMD * DHEAVY * 2)    // wh2t
                 + rnd((size_t)NTOK * DIMD * 2)      // xb
                 + rnd((size_t)NSEL * DHEAVY * 2)    // hh
                 + rnd((size_t)NTOK * DLIGHT * 2)    // hl
                 + rnd((size_t)NSEL * DIMD * 4);     // hv (f32)
    int nsk = 4;
    while (nsk > 1 && fixed + rnd((size_t)nsk * NSEL * DIMD * 2) > ws_size) nsk >>= 1;

    char* base = (char*)d_ws;
    size_t off = 0;
    auto alloc = [&](size_t bytes) -> void* {
        void* p = base + off;
        off += rnd(bytes);
        return p;
    };
    double* s     = (double*)alloc(NTOK * sizeof(double));
    int*    sel   = (int*)alloc(NSEL * sizeof(int));
    int*    inv   = (int*)alloc(NTOK * sizeof(int));
    float*  sc    = (float*)alloc(NTOK * sizeof(float));
    short*  wl1t  = (short*)alloc((size_t)DLIGHT * DIMD * 2);
    short*  wl2t  = (short*)alloc((size_t)DIMD * DLIGHT * 2);
    short*  wh1t  = (short*)alloc((size_t)DHEAVY * DIMD * 2);
    short*  wh2t  = (short*)alloc((size_t)DIMD * DHEAVY * 2);
    short*  xb    = (short*)alloc((size_t)NTOK * DIMD * 2);
    short*  hh    = (short*)alloc((size_t)NSEL * DHEAVY * 2);
    short*  hl    = (short*)alloc((size_t)NTOK * DLIGHT * 2);
    float*  hv    = (float*)alloc((size_t)NSEL * DIMD * 4);
    short*  phb   = (short*)alloc((size_t)nsk * NSEL * DIMD * 2);

    // fused init: 4x weight cvt_transpose (gamma folded into W1) + xpass + inv=-1
    fused_init<<<9216 + NTOK, 256, 0, stream>>>(
        lw1, lw2, hw1, hw2, lgamma, hgamma,
        wl1t, wl2t, wh1t, wh2t,
        x, rt, (unsigned short*)xb, sc, s, inv);

    // megakernel: descent+select (blocks 0-3) || light GEMM1 (blocks 4-1027)
    mega_kern<<<4 + 1024, 256, 0, stream>>>(
        s, sel, inv, xb, wl1t, lb1, sc, (__hip_bfloat16*)hl);

    // heavy: GEMM1 (gather rows of xb, sc+gelu epi) -> hh; GEMM2 split-K -> phb; reduce -> hv
    gemm256<0, true><<<dim3(DHEAVY / 256, NSEL / 256), 512, 0, stream>>>(
        xb, wh1t, hb1, sc, sel, nullptr, nullptr,
        nullptr, (__hip_bfloat16*)hh, NSEL, DHEAVY, DIMD);
    gemm256<2, false><<<dim3(DIMD / 256, NSEL / 256, nsk), 512, 0, stream>>>(
        hh, wh2t, nullptr, nullptr, nullptr, nullptr, nullptr,
        nullptr, (__hip_bfloat16*)phb, NSEL, DIMD, DHEAVY);
    reduce_hv_kern<<<NSEL, 256, 0, stream>>>((const unsigned short*)phb, hb2, hv, nsk);

    // light GEMM2 fused (+hv via inv) -> out
    gemm256<3, false><<<dim3(DIMD / 256, NTOK / 256), 512, 0, stream>>>(
        hl, wl2t, lb2, nullptr, nullptr, inv, hv,
        out, nullptr, NTOK, DIMD, DLIGHT);
}